// Round 6
// baseline (1032.219 us; speedup 1.0000x reference)
//
#include <hip/hip_runtime.h>
#include <cstddef>

// ---------------------------------------------------------------------------
// TransformerXL forward on gfx950.  T=512 B=16 D=512 H=8 DH=64 DI=2048 L=4.
// All matmuls bf16 MFMA (16x16x32), fp32 accum. LN / softmax fp32.
// ---------------------------------------------------------------------------

typedef unsigned short u16;
typedef short s16x8 __attribute__((ext_vector_type(8)));
typedef unsigned short u16x8 __attribute__((ext_vector_type(8)));
typedef float f32x4 __attribute__((ext_vector_type(4)));

__device__ __forceinline__ u16 f2bf(float f) {  // RNE float->bf16
  unsigned int u = __float_as_uint(f);
  u += 0x7fffu + ((u >> 16) & 1u);
  return (u16)(u >> 16);
}
__device__ __forceinline__ float bf2f(u16 u) {
  return __uint_as_float((unsigned int)u << 16);
}

__device__ __forceinline__ f32x4 mfma16(s16x8 a, s16x8 b, f32x4 c) {
  return __builtin_amdgcn_mfma_f32_16x16x32_bf16(a, b, c, 0, 0, 0);
}

__device__ __forceinline__ void gl2lds16(const u16* g, u16* l) {
  __builtin_amdgcn_global_load_lds(
      (const __attribute__((address_space(1))) unsigned int*)g,
      (__attribute__((address_space(3))) unsigned int*)l, 16, 0, 0);
}

// ---------------------------------------------------------------------------
// Generic bf16 GEMM: C(M,N) = A(M,K) * Bt(N,K)^T ; 128xTN tile, BK=64,
// 256 threads = 4 waves in 2x2. TN=128 or 64 (64 doubles grid for small N).
// XOR chunk swizzle (chunk ^= row&7) on the 64-u16-row LDS tiles, computed on
// the per-lane GLOBAL address (LDS dest lane-contiguous per gl2lds contract).
//
// 2-PHASE PIPELINE (T3 minimum recipe): LDS double-buffered; iteration kt
// issues gl2lds for tile kt+1 into buf^1 BEFORE computing tile kt from buf,
// then ends with {lgkmcnt(0); vmcnt(0); s_barrier} -- the vmcnt(0) waits for
// loads that had the whole MFMA phase to land (vs the old __syncthreads
// drain immediately after the stage = full serial L2 latency per kt).
// Safety: buf^1 was last READ at iteration kt-1, and every wave passed the
// end-of-(kt-1) barrier (with its lgkmcnt(0)) before any wave issues the
// kt-stage into it. No extra VGPRs (round-3 spill lesson): state is in LDS.
// LDS: TN=128 -> 64 KB (2 blocks/CU), TN=64 -> 48 KB (3 blocks/CU).
//
// MODE 0: rk epilogue, ALL LAYERS batched: blockIdx.z = layer*2+group;
//         A = r_bf (+group), Bt = rnetT base (+layer), p0 = rkb bf16
//         [layer][group][head][1024][64].
// MODE 1: qkv split    -> Qw(+rwb) Qr(+rrb) Kb Vb bf16 (p0..p3,p4,p5)
// MODE 2: + residual   -> f32 p0 = C + p1
// MODE 3: + res + bias -> f32 p0 = C + p1 + bias(p2)
// MODE 4: bias + relu  -> bf16 p0 = relu(C + bias(p1))
// ---------------------------------------------------------------------------
template <int MODE, int TN>
__launch_bounds__(256) __global__
void gemm_bt(const u16* __restrict__ A, const u16* __restrict__ Bt,
             int M, int N, int K,
             void* p0, void* p1, void* p2, void* p3,
             const float* __restrict__ p4, const float* __restrict__ p5) {
  (void)M;
  constexpr int NT = TN / 32;   // n-tiles (16 wide) per wave
  constexpr int NBQ = TN / 32;  // B staging instrs per wave (4 or 2)
  constexpr int BH = TN * 64;   // Bs half size (u16)
  __shared__ u16 As[2 * 8192];
  __shared__ u16 Bs[2 * BH];
  const int tid = threadIdx.x;
  const int lane = tid & 63;
  const int w = tid >> 6;
  const int quad = lane >> 4, l15 = lane & 15;
  const int m0 = blockIdx.y << 7, n0 = blockIdx.x * TN;

  if constexpr (MODE == 0) {
    const int lz = blockIdx.z >> 1, gz = blockIdx.z & 1;
    A += (size_t)gz * 524288;          // group offset in r_bf
    Bt += (size_t)lz * 262144;         // per-layer rnetT
    p0 = (void*)((u16*)p0 + (size_t)lz * 1048576 + (size_t)gz * 524288);
  }

  f32x4 acc[4][NT];
#pragma unroll
  for (int a = 0; a < 4; ++a)
#pragma unroll
    for (int b = 0; b < NT; ++b) {
      f32x4 z = {0.f, 0.f, 0.f, 0.f};
      acc[a][b] = z;
    }

  // Staging: per instr, wave w covers 8 rows (8 rows x 64 u16 = 1 KB).
  const int rg = lane >> 3;
  const int cz = ((lane & 7) ^ rg) << 3;  // swizzled u16 col offset
  const u16* gA = A + (size_t)(m0 + w * 8 + rg) * K + cz;
  const u16* gB = Bt + (size_t)(n0 + w * 8 + rg) * K + cz;
  u16* lA = &As[w * 512];
  u16* lB = &Bs[w * 512];

  const int wm = (w >> 1) << 6, wn = (w & 1) * (NT * 16);
  const int rsw = l15 & 7;  // fragment row&7 (wm, t*16 are multiples of 8)
  const int nk = K >> 6;

  auto stage = [&](int kt, int sel) {
    const int k0 = kt << 6;
    u16* dA = lA + sel * 8192;
    u16* dB = lB + sel * BH;
#pragma unroll
    for (int q = 0; q < 4; ++q)  // A: rows q*32 + w*8 + rg
      gl2lds16(gA + (size_t)(q * 32) * K + k0, dA + q * 2048);
#pragma unroll
    for (int q = 0; q < NBQ; ++q)
      gl2lds16(gB + (size_t)(q * 32) * K + k0, dB + q * 2048);
  };

  stage(0, 0);
  __syncthreads();  // prologue: full drain (vmcnt 0) once

  for (int kt = 0; kt < nk; ++kt) {
    const int sel = kt & 1;
    if (kt + 1 < nk) stage(kt + 1, sel ^ 1);
    __builtin_amdgcn_sched_barrier(0);  // pin: stage issued before compute
    const int ab = sel * 8192, bb = sel * BH;
#pragma unroll
    for (int ks = 0; ks < 2; ++ks) {
      // global chunk g = ks*4+quad of row r lives at LDS chunk g ^ (r&7)
      const int co = ((ks * 4 + quad) ^ rsw) << 3;
      s16x8 af[4], bfg[NT];
#pragma unroll
      for (int t = 0; t < 4; ++t)
        af[t] = *(const s16x8*)&As[ab + (wm + t * 16 + l15) * 64 + co];
#pragma unroll
      for (int t = 0; t < NT; ++t)
        bfg[t] = *(const s16x8*)&Bs[bb + (wn + t * 16 + l15) * 64 + co];
#pragma unroll
      for (int mt = 0; mt < 4; ++mt)
#pragma unroll
        for (int nt = 0; nt < NT; ++nt)
          acc[mt][nt] = mfma16(af[mt], bfg[nt], acc[mt][nt]);
    }
    // End-of-iter sync: ds_reads drained (consumed by MFMA), next-tile loads
    // landed (they had the whole compute phase), then barrier.
    asm volatile("s_waitcnt lgkmcnt(0)" ::: "memory");
    asm volatile("s_waitcnt vmcnt(0)" ::: "memory");
    __builtin_amdgcn_s_barrier();
    __builtin_amdgcn_sched_barrier(0);
  }

#pragma unroll
  for (int mt = 0; mt < 4; ++mt) {
#pragma unroll
    for (int nt = 0; nt < NT; ++nt) {
#pragma unroll
      for (int r = 0; r < 4; ++r) {
        const int row = m0 + wm + mt * 16 + quad * 4 + r;
        const int col = n0 + wn + nt * 16 + l15;
        const float v = acc[mt][nt][r];
        if constexpr (MODE == 0) {
          const int hn = col >> 6, d = col & 63;
          ((u16*)p0)[((size_t)hn * 1024 + row) * 64 + d] = f2bf(v);
        } else if constexpr (MODE == 1) {
          const int i = row >> 4, b = row & 15;
          const int which = col >> 9, hn = (col >> 6) & 7, d = col & 63;
          const int bn = b * 8 + hn;
          const size_t idx = ((size_t)bn * 512 + i) * 64 + d;
          if (which == 0) {
            ((u16*)p0)[idx] = f2bf(v + p4[hn * 64 + d]);
            ((u16*)p1)[idx] = f2bf(v + p5[hn * 64 + d]);
          } else if (which == 1) {
            ((u16*)p2)[idx] = f2bf(v);
          } else {
            ((u16*)p3)[idx] = f2bf(v);
          }
        } else if constexpr (MODE == 2) {
          ((float*)p0)[(size_t)row * N + col] =
              v + ((const float*)p1)[(size_t)row * N + col];
        } else if constexpr (MODE == 3) {
          ((float*)p0)[(size_t)row * N + col] =
              v + ((const float*)p1)[(size_t)row * N + col] +
              ((const float*)p2)[col];
        } else {
          float t = v + ((const float*)p1)[col];
          ((u16*)p0)[(size_t)row * N + col] = f2bf(t > 0.f ? t : 0.f);
        }
      }
    }
  }
}

// ---------------------------------------------------------------------------
// Weight transpose+convert: src f32 (R,C) -> dst bf16 (C,R). 64x64 tiles.
// ---------------------------------------------------------------------------
__launch_bounds__(256) __global__
void transpose_w_kernel(const float* __restrict__ qkv, const float* __restrict__ rnet,
                        const float* __restrict__ ow, const float* __restrict__ w1,
                        const float* __restrict__ w2, u16* __restrict__ dst) {
  const int type = blockIdx.z, l = blockIdx.y, tile = blockIdx.x;
  int R, C;
  const float* src;
  u16* out;
  switch (type) {
    case 0: R = 512; C = 1536; src = qkv + (size_t)l * 786432; out = dst + (size_t)l * 786432; break;
    case 1: R = 512; C = 512;  src = rnet + (size_t)l * 262144; out = dst + 3145728 + (size_t)l * 262144; break;
    case 2: R = 512; C = 512;  src = ow + (size_t)l * 262144;   out = dst + 4194304 + (size_t)l * 262144; break;
    case 3: R = 512; C = 2048; src = w1 + (size_t)l * 1048576;  out = dst + 5242880 + (size_t)l * 1048576; break;
    default: R = 2048; C = 512; src = w2 + (size_t)l * 1048576; out = dst + 9437184 + (size_t)l * 1048576; break;
  }
  const int tC = C >> 6;
  const int tR = R >> 6;
  if (tile >= tC * tR) return;
  const int r0 = (tile / tC) << 6, c0 = (tile % tC) << 6;
  __shared__ float tb[64][65];
  const int tid = threadIdx.x;
  const int rr = tid >> 2, cc = (tid & 3) << 4;
#pragma unroll
  for (int j = 0; j < 4; ++j) {
    f32x4 u = *(const f32x4*)(src + (size_t)(r0 + rr) * C + c0 + cc + j * 4);
    tb[rr][cc + j * 4 + 0] = u[0];
    tb[rr][cc + j * 4 + 1] = u[1];
    tb[rr][cc + j * 4 + 2] = u[2];
    tb[rr][cc + j * 4 + 3] = u[3];
  }
  __syncthreads();
  u16x8 o0, o1;
#pragma unroll
  for (int j = 0; j < 8; ++j) o0[j] = f2bf(tb[cc + j][rr]);
#pragma unroll
  for (int j = 0; j < 8; ++j) o1[j] = f2bf(tb[cc + 8 + j][rr]);
  *(u16x8*)(out + (size_t)(c0 + rr) * R + r0 + cc) = o0;
  *(u16x8*)(out + (size_t)(c0 + rr) * R + r0 + cc + 8) = o1;
}

// ---------------------------------------------------------------------------
// Positional embeddings: r_bf[g][j][d], g=0 fw (pos=512-j), g=1 bw (pos=j-512)
// ---------------------------------------------------------------------------
__launch_bounds__(256) __global__
void posemb_kernel(u16* __restrict__ r_bf) {
  const int idx = blockIdx.x * 256 + threadIdx.x;  // 2*1024*512
  const int d = idx & 511, j = (idx >> 9) & 1023, g = idx >> 19;
  const float pos = g ? (float)(j - 512) : (float)(512 - j);
  const int dp = d & 255;
  const float invf = expf((float)dp * (-9.210340371976184f / 256.f));
  const float v = pos * invf;
  r_bf[idx] = f2bf((d < 256) ? sinf(v) : cosf(v));
}

// ---------------------------------------------------------------------------
// V transpose per layer: Vb[bn][j][d] -> Vt[bn][d][j] (bf16), 64-key tiles.
// ---------------------------------------------------------------------------
__launch_bounds__(256) __global__
void transpose_v_kernel(const u16* __restrict__ Vb, u16* __restrict__ Vt) {
  const int bn = blockIdx.y, j0 = blockIdx.x << 6;
  __shared__ u16 tb[64][72];
  const int tid = threadIdx.x;
#pragma unroll
  for (int q = 0; q < 2; ++q) {
    const int s = q * 256 + tid;
    const int jj = s >> 3, c = s & 7;
    u16x8 u = *(const u16x8*)(Vb + ((size_t)bn * 512 + j0 + jj) * 64 + c * 8);
    *(u16x8*)&tb[jj][c * 8] = u;
  }
  __syncthreads();
#pragma unroll
  for (int q = 0; q < 2; ++q) {
    const int s = q * 256 + tid;
    const int d = s >> 3, c = s & 7;
    u16x8 o;
#pragma unroll
    for (int e = 0; e < 8; ++e) o[e] = tb[c * 8 + e][d];
    *(u16x8*)(Vt + ((size_t)bn * 64 + d) * 512 + j0 + c * 8) = o;
  }
}

// ---------------------------------------------------------------------------
// Fused rel-attention, flash-style. Block = one (b,head) x 64 queries; 4 waves.
// LDS = 40960 B -> 4 blocks/CU. Grid (bn, i0): the 8 i0-blocks sharing one
// (b,head)'s K/V/rk get ids === bn (mod 8) -> same XCD -> fetched once, L2-hot.
//
// PIPELINED (T14 + counted waits), proven in round 5 (attn 60.5 -> <58, no
// spill with default launch bounds). During compute of tile jt, the 6
// 16B/lane global loads for tile jt+1 are in flight into registers; at iter
// jt+1 they are ds_written into the SAME single-buffered LDS. Barriers are
// raw s_barrier + lgkmcnt(0) -- NO vmcnt(0) in the main loop. Only the jt==0
// prologue uses a counted vmcnt(6).
//   - mask:  per-thread 32-bit register mask; loop jt < ntiles (prefix).
//   - Band ring: stage 128 rows at jt=0, then 64 new rows/tile; phys row =
//            (off + 64*jt) & 127; at iter jt the commit writes segments
//            ((jt+1)&1)*2,+1 (the 64 oldest rows, dead after the barrier).
//   - BD rel-shift: in-quad __shfl gather, fp32, no LDS scratch.
//   - P buffer [16][64] XOR-chunk swizzled; conflict-free b128 reads.
// XOR chunk swizzle (c ^= row&7) on all 64-u16-row LDS tiles: staging
// computes the swizzle on the per-lane GLOBAL address (LDS dest stays
// lane-contiguous); fragment reads mirror it.
// ---------------------------------------------------------------------------
#define ATTN_FENCE_BAR()                                    \
  do {                                                      \
    asm volatile("s_waitcnt lgkmcnt(0)" ::: "memory");      \
    __builtin_amdgcn_s_barrier();                           \
    __builtin_amdgcn_sched_barrier(0);                      \
  } while (0)

__launch_bounds__(256) __global__
void attn_kernel(const u16* __restrict__ Qw, const u16* __restrict__ Qr,
                 const u16* __restrict__ Kb, const u16* __restrict__ Vt,
                 const u16* __restrict__ rkb, const int* __restrict__ smask,
                 u16* __restrict__ vecb) {
  __shared__ u16 Ks[4096];    // [key][d]   64x64, swizzled
  __shared__ u16 Vts[4096];   // [d][key]   64x64, swizzled
  __shared__ u16 Band[8192];  // [band][d] 128x64, swizzled, 64-row ring
  __shared__ u16 Ps[4096];    // per wave [16][64], XOR-chunk swizzled

  const int tid = threadIdx.x, lane = tid & 63, w = tid >> 6;
  const int quad = lane >> 4, l15 = lane & 15;
  const int bn = blockIdx.x, b = bn >> 3, n = bn & 7;
  const int g = (b >= 8) ? 1 : 0;
  const int i0 = blockIdx.y << 6;

  // Per-thread mask bits: bit s (s=0..31) = smask[b*512 + s*16 + l15] != 0.
  unsigned mbits = 0;
  const int* smb = smask + b * 512 + l15;
#pragma unroll
  for (int s = 0; s < 32; ++s)
    if (smb[s * 16]) mbits |= 1u << s;
  // Wave-uniform valid-tile mask (identical across all 4 waves).
  unsigned vmask = 0;
#pragma unroll
  for (int jt = 0; jt < 8; ++jt)
    if (__any((int)((mbits >> (jt * 4)) & 15u))) vmask |= 1u << jt;
  const int ntiles = vmask ? (32 - __clz((int)vmask)) : 0;

  const u16* qwp = Qw + ((size_t)bn * 512 + i0 + w * 16 + l15) * 64 + quad * 8;
  const u16* qrp = Qr + ((size_t)bn * 512 + i0 + w * 16 + l15) * 64 + quad * 8;
  const s16x8 qw0 = *(const s16x8*)qwp, qw1 = *(const s16x8*)(qwp + 32);
  const s16x8 qr0 = *(const s16x8*)qrp, qr1 = *(const s16x8*)(qrp + 32);

  const u16* kbase = Kb + (size_t)bn * (512 * 64);
  const u16* vbase = Vt + (size_t)bn * (64 * 512);
  const u16* rkg = rkb + (size_t)(g * 8 + n) * (1024 * 64);

  const int s0 = w * 64 + lane;
  const int rl = s0 >> 3;                   // LDS row within 32-row instr
  const int cd = ((s0 & 7) ^ (rl & 7)) * 8; // swizzled data chunk (u16 offset)
  u16* lK0 = &Ks[w * 512];
  u16* lK1 = &Ks[(4 + w) * 512];
  u16* lV0 = &Vts[w * 512];
  u16* lV1 = &Vts[(4 + w) * 512];
  u16* lBq[4] = {&Band[w * 512], &Band[(4 + w) * 512], &Band[(8 + w) * 512],
                 &Band[(12 + w) * 512]};
  u16* pwv = &Ps[w * 1024];

  // fragment-read swizzle: chunk quad -> quad ^ (row&7); row&7 == l15&7 here
  const int sw8 = ((quad ^ (l15 & 7)) * 8);
  const int sw8b = (((quad ^ (l15 & 7)) ^ 4) * 8);

  // rel-shift gather lanes: dest (quad,l15,r) needs band element at
  // k = 15 + nj - mi (nj = t*16+l15, mi = quad*4+r). With e = 15+l15-mi:
  // source tile = t + (e>>4), source lane = quad*16 + (e&15), reg = r.
  int sl[4], hisel[4];
#pragma unroll
  for (int r = 0; r < 4; ++r) {
    const int e = 15 + l15 - quad * 4 - r;
    sl[r] = (quad << 4) | (e & 15);
    hisel[r] = e >> 4;
  }

  f32x4 O[4];
  float m_st[4], l_st[4];
#pragma unroll
  for (int t = 0; t < 4; ++t) {
    f32x4 z = {0.f, 0.f, 0.f, 0.f};
    O[t] = z;
    m_st[t] = -1e30f;
    l_st[t] = 0.f;
  }

  // Prefetch registers for tile jt+1 (K hi/lo, V hi/lo, Band new-64-rows).
  s16x8 rK0, rK1, rV0, rV1, rB0, rB1;
  auto issue_prefetch = [&](int nt) {  // nt = tile index being prefetched
    const int j0n = nt << 6;
    const int jr0n = 449 + j0n - i0;
    rK0 = *(const s16x8*)(kbase + (size_t)(j0n + rl) * 64 + cd);
    rK1 = *(const s16x8*)(kbase + (size_t)(j0n + 32 + rl) * 64 + cd);
    rV0 = *(const s16x8*)(vbase + (size_t)rl * 512 + j0n + cd);
    rV1 = *(const s16x8*)(vbase + (size_t)(rl + 32) * 512 + j0n + cd);
    int rr0 = jr0n + 64 + rl;
    int rr1 = jr0n + 96 + rl;
    rr0 = rr0 < 1023 ? rr0 : 1023;  // last band row unused; avoid OOB
    rr1 = rr1 < 1023 ? rr1 : 1023;
    rB0 = *(const s16x8*)(rkg + (size_t)rr0 * 64 + cd);
    rB1 = *(const s16x8*)(rkg + (size_t)rr1 * 64 + cd);
  };

  for (int jt = 0; jt < ntiles; ++jt) {
    if (jt == 0) {
      // Full stage of tile 0 via gl2lds (no extra registers), then issue
      // tile-1 prefetch, then counted vmcnt: waits the 8 gl2lds only.
      const int jr00 = 449 - i0;
      gl2lds16(kbase + (size_t)rl * 64 + cd, lK0);
      gl2lds16(kbase + (size_t)(32 + rl) * 64 + cd, lK1);
      gl2lds16(vbase + (size_t)rl * 512 + cd, lV0);
      gl2lds16(vbase + (size_t)(rl + 32) * 512 + cd, lV1);
#pragma unroll
      for (int q = 0; q < 4; ++q) {
        int rrow = jr00 + q * 32 + rl;
        rrow = rrow < 1023 ? rrow : 1023;
        gl2lds16(rkg + (size_t)rrow * 64 + cd, lBq[q]);
      }
      asm volatile("" ::: "memory");  // pin: gl2lds issued before prefetch
      __builtin_amdgcn_sched_barrier(0);
      if (ntiles > 1) {
        issue_prefetch(1);
        asm volatile("s_waitcnt vmcnt(6)" ::: "memory");  // 8 gl2lds done
      } else {
        asm volatile("s_waitcnt vmcnt(0)" ::: "memory");
      }
      __builtin_amdgcn_s_barrier();
      __builtin_amdgcn_sched_barrier(0);
    } else {
      // All waves finished reading LDS for jt-1 (every ds_read was consumed
      // by an MFMA before this point).
      ATTN_FENCE_BAR();
      // Commit prefetched tile jt to LDS (same addresses gl2lds used).
      // Compiler auto-waits vmcnt for the prefetch regs here (they had the
      // whole previous compute phase to land).
      *(s16x8*)(lK0 + lane * 8) = rK0;
      *(s16x8*)(lK1 + lane * 8) = rK1;
      *(s16x8*)(lV0 + lane * 8) = rV0;
      *(s16x8*)(lV1 + lane * 8) = rV1;
      const int segb = ((jt + 1) & 1) << 1;  // ring segments for new rows
      *(s16x8*)(lBq[segb] + lane * 8) = rB0;
      *(s16x8*)(lBq[segb + 1] + lane * 8) = rB1;
      if (jt + 1 < ntiles) issue_prefetch(jt + 1);
      ATTN_FENCE_BAR();  // lgkmcnt(0): ds_writes visible; loads stay in flight
    }

    // AC = (q+rwb) . K^T
    f32x4 ac[4];
#pragma unroll
    for (int t = 0; t < 4; ++t) {
      f32x4 z = {0.f, 0.f, 0.f, 0.f};
      ac[t] = z;
      s16x8 k0f = *(const s16x8*)&Ks[(t * 16 + l15) * 64 + sw8];
      s16x8 k1f = *(const s16x8*)&Ks[(t * 16 + l15) * 64 + sw8b];
      ac[t] = mfma16(qw0, k0f, ac[t]);
      ac[t] = mfma16(qw1, k1f, ac[t]);
    }
    // BD band: wave w covers band rows [48-16w, 128-16w), ring-offset reads
    const int bb0 = 48 - w * 16;
    const int rofs = (jt & 1) << 6;
    f32x4 bd[5];
#pragma unroll
    for (int t = 0; t < 5; ++t) {
      f32x4 z = {0.f, 0.f, 0.f, 0.f};
      const int prow = ((bb0 + t * 16 + l15) + rofs) & 127;
      s16x8 b0f = *(const s16x8*)&Band[prow * 64 + sw8];
      s16x8 b1f = *(const s16x8*)&Band[prow * 64 + sw8b];
      bd[t] = mfma16(qr1, b1f, mfma16(qr0, b0f, z));
    }
    // rel-shift via in-quad bpermute; sh[t] doubles as hi of tile t-1
    float sh[5][4];
#pragma unroll
    for (int t = 0; t < 5; ++t)
#pragma unroll
      for (int r = 0; r < 4; ++r) sh[t][r] = __shfl(bd[t][r], sl[r]);

    // combine + scale + mask
    float pv[4][4];
#pragma unroll
    for (int t = 0; t < 4; ++t) {
      const float mk = ((mbits >> (jt * 4 + t)) & 1u) ? 0.f : -1e9f;
#pragma unroll
      for (int r = 0; r < 4; ++r) {
        const float bdv = hisel[r] ? sh[t + 1][r] : sh[t][r];
        pv[t][r] = (ac[t][r] + bdv) * 0.125f + mk;
      }
    }
    // online softmax per C-row (16-lane butterfly within l15 group)
#pragma unroll
    for (int r = 0; r < 4; ++r) {
      float mx = fmaxf(fmaxf(pv[0][r], pv[1][r]), fmaxf(pv[2][r], pv[3][r]));
#pragma unroll
      for (int xm = 1; xm < 16; xm <<= 1) mx = fmaxf(mx, __shfl_xor(mx, xm));
      const float mn = fmaxf(m_st[r], mx);
      const float al = __expf(m_st[r] - mn);
      m_st[r] = mn;
      float rs = 0.f;
#pragma unroll
      for (int t = 0; t < 4; ++t) {
        pv[t][r] = __expf(pv[t][r] - mn);
        rs += pv[t][r];
      }
#pragma unroll
      for (int xm = 1; xm < 16; xm <<= 1) rs += __shfl_xor(rs, xm);
      l_st[r] = l_st[r] * al + rs;
#pragma unroll
      for (int t = 0; t < 4; ++t) O[t][r] *= al;
    }
    // P -> LDS ([16][64] XOR-chunk swizzled), PV MFMA. Ps is per-wave
    // private, so same-wave DS ordering makes this race-free.
#pragma unroll
    for (int t = 0; t < 4; ++t)
#pragma unroll
      for (int r = 0; r < 4; ++r) {
        const int row = quad * 4 + r, col = t * 16 + l15;
        pwv[row * 64 + ((((col >> 3) ^ row) & 7) << 3) + (col & 7)] =
            f2bf(pv[t][r]);
      }
#pragma unroll
    for (int ks = 0; ks < 2; ++ks) {
      const int ch = (((ks * 4 + quad) ^ l15) & 7) << 3;
      s16x8 pf = *(const s16x8*)&pwv[l15 * 64 + ch];
#pragma unroll
      for (int td = 0; td < 4; ++td) {
        s16x8 vf = *(const s16x8*)&Vts[(td * 16 + l15) * 64 +
                                       (ks == 0 ? sw8 : sw8b)];
        O[td] = mfma16(pf, vf, O[td]);
      }
    }
  }

#pragma unroll
  for (int td = 0; td < 4; ++td) {
#pragma unroll
    for (int r = 0; r < 4; ++r) {
      const int i = i0 + w * 16 + quad * 4 + r;
      const float val = O[td][r] / l_st[r];
      vecb[((size_t)i * 16 + b) * 512 + n * 64 + td * 16 + l15] = f2bf(val);
    }
  }
}

// ---------------------------------------------------------------------------
// LayerNorm over D=512, 1 wave per row. row = i*B+b. Optional outputs:
// dst32 f32 (T,B,D), dstbf bf16 (T,B,D), o1/o2 f32 (B,T,D) (for d_out).
// ---------------------------------------------------------------------------
__launch_bounds__(256) __global__
void ln_kernel(const float* __restrict__ src, int src_is_bt,
               const float* __restrict__ gw, const float* __restrict__ bww,
               float* __restrict__ dst32, u16* __restrict__ dstbf,
               float* __restrict__ o1, float* __restrict__ o2) {
  const int row = blockIdx.x * 4 + (threadIdx.x >> 6);
  const int lane = threadIdx.x & 63;
  const int i = row >> 4, b = row & 15;
  const float* x = src + (src_is_bt ? ((size_t)b * 512 + i) * 512 : (size_t)row * 512);
  f32x4 u0 = *(const f32x4*)(x + lane * 8);
  f32x4 u1 = *(const f32x4*)(x + lane * 8 + 4);
  float s = u0[0] + u0[1] + u0[2] + u0[3] + u1[0] + u1[1] + u1[2] + u1[3];
  float sq = u0[0] * u0[0] + u0[1] * u0[1] + u0[2] * u0[2] + u0[3] * u0[3] +
             u1[0] * u1[0] + u1[1] * u1[1] + u1[2] * u1[2] + u1[3] * u1[3];
  for (int m = 1; m < 64; m <<= 1) {
    s += __shfl_xor(s, m);
    sq += __shfl_xor(sq, m);
  }
  const float mean = s * (1.f / 512.f);
  const float var = sq * (1.f / 512.f) - mean * mean;
  const float rs = rsqrtf(var + 1e-6f);
  f32x4 g0 = *(const f32x4*)(gw + lane * 8);
  f32x4 g1 = *(const f32x4*)(gw + lane * 8 + 4);
  f32x4 b0 = *(const f32x4*)(bww + lane * 8);
  f32x4 b1 = *(const f32x4*)(bww + lane * 8 + 4);
  f32x4 y0, y1;
#pragma unroll
  for (int k = 0; k < 4; ++k) {
    y0[k] = (u0[k] - mean) * rs * g0[k] + b0[k];
    y1[k] = (u1[k] - mean) * rs * g1[k] + b1[k];
  }
  const size_t o_ib = (size_t)row * 512 + lane * 8;
  const size_t o_tb = ((size_t)b * 512 + i) * 512 + lane * 8;
  if (dst32) {
    *(f32x4*)(dst32 + o_ib) = y0;
    *(f32x4*)(dst32 + o_ib + 4) = y1;
  }
  if (dstbf) {
    u16x8 ov;
#pragma unroll
    for (int k = 0; k < 4; ++k) {
      ov[k] = f2bf(y0[k]);
      ov[k + 4] = f2bf(y1[k]);
    }
    *(u16x8*)(dstbf + o_ib) = ov;
  }
  if (o1) {
    *(f32x4*)(o1 + o_tb) = y0;
    *(f32x4*)(o1 + o_tb + 4) = y1;
  }
  if (o2) {
    *(f32x4*)(o2 + o_tb) = y0;
    *(f32x4*)(o2 + o_tb + 4) = y1;
  }
}

// ---------------------------------------------------------------------------
extern "C" void kernel_launch(void* const* d_in, const int* in_sizes, int n_in,
                              void* d_out, int out_size, void* d_ws, size_t ws_size,
                              hipStream_t stream) {
  (void)in_sizes; (void)n_in; (void)out_size; (void)ws_size;
  const float* h_in = (const float*)d_in[0];
  const int* smask = (const int*)d_in[1];  // bool -> int32 per harness contract
  const float* rwb = (const float*)d_in[2];
  const float* rrb = (const float*)d_in[3];
  const float* top_g = (const float*)d_in[4];
  const float* top_b = (const float*)d_in[5];
  const float* qkv_w = (const float*)d_in[6];
  const float* rnet_w = (const float*)d_in[7];
  const float* o_w = (const float*)d_in[8];
  const float* attn_g = (const float*)d_in[9];
  const float* attn_b = (const float*)d_in[10];
  const float* w1 = (const float*)d_in[11];
  const float* b1 = (const float*)d_in[12];
  const float* w2 = (const float*)d_in[13];
  const float* b2 = (const float*)d_in[14];
  const float* ff_g = (const float*)d_in[15];
  const float* ff_b = (const float*)d_in[16];
  float* out = (float*)d_out;
  const size_t BTD = 4194304;  // 16*512*512

  char* ws = (char*)d_ws;
  size_t off = 0;
  auto alloc = [&](size_t bytes) {
    void* p = ws + off;
    off += (bytes + 255) & ~(size_t)255;
    return p;
  };
  u16* wT = (u16*)alloc(13631488ull * 2);       // transposed bf16 weights
  u16* r_bf = (u16*)alloc(2ull * 1024 * 512 * 2);
  u16* rkb = (u16*)alloc(8ull << 20);           // 4 layers x 2 groups x 8 x 1024 x 64 bf16
  u16* Qw = (u16*)alloc(8ull << 20);
  u16* Qr = (u16*)alloc(8ull << 20);
  u16* Kb = (u16*)alloc(8ull << 20);
  u16* Vt = (u16*)alloc(8ull << 20);
  u16* vecb = (u16*)alloc(8ull << 20);
  u16* Xbf = (u16*)alloc(8ull << 20);
  u16* ffbf = (u16*)alloc(32ull << 20);
  float* hcur = (float*)alloc(16ull << 20);
  // aliases (lifetimes verified): tmp over Qw+Qr, mid over Kb+Vt, Vb over ffbf[0:8MB]
  float* tmp = (float*)Qw;
  float* mid = (float*)Kb;
  u16* Vb = ffbf;

  dim3 blk(256);
  transpose_w_kernel<<<dim3(256, 4, 5), blk, 0, stream>>>(qkv_w, rnet_w, o_w, w1, w2, wT);
  posemb_kernel<<<dim3(4096), blk, 0, stream>>>(r_bf);
  ln_kernel<<<dim3(2048), blk, 0, stream>>>(h_in, 1, top_g, top_b, hcur, Xbf,
                                            out + BTD, (float*)nullptr);

  // All 4 layers' rk GEMMs batched (activation-independent): z = layer*2+group
  gemm_bt<0, 64><<<dim3(8, 8, 8), blk, 0, stream>>>(
      r_bf, wT + 3145728, 1024, 512, 512,
      rkb, nullptr, nullptr, nullptr, nullptr, nullptr);

  for (int l = 0; l < 4; ++l) {
    u16* qkvT = wT + (size_t)l * 786432;
    u16* oT = wT + 4194304 + (size_t)l * 262144;
    u16* w1T = wT + 5242880 + (size_t)l * 1048576;
    u16* w2T = wT + 9437184 + (size_t)l * 1048576;

    gemm_bt<1, 128><<<dim3(12, 64), blk, 0, stream>>>(
        Xbf, qkvT, 8192, 1536, 512, Qw, Qr, Kb, Vb, rwb, rrb);

    transpose_v_kernel<<<dim3(8, 128), blk, 0, stream>>>(Vb, Vt);

    attn_kernel<<<dim3(128, 8), blk, 0, stream>>>(
        Qw, Qr, Kb, Vt, rkb + (size_t)l * 1048576, smask, vecb);

    gemm_bt<2, 64><<<dim3(8, 64), blk, 0, stream>>>(
        vecb, oT, 8192, 512, 512, tmp, hcur, nullptr, nullptr, nullptr, nullptr);

    ln_kernel<<<dim3(2048), blk, 0, stream>>>(tmp, 0, attn_g + l * 512, attn_b + l * 512,
                                              mid, Xbf, (float*)nullptr, (float*)nullptr);

    gemm_bt<4, 128><<<dim3(16, 64), blk, 0, stream>>>(
        Xbf, w1T, 8192, 2048, 512, ffbf, (void*)(b1 + (size_t)l * 2048),
        nullptr, nullptr, nullptr, nullptr);

    gemm_bt<3, 64><<<dim3(8, 64), blk, 0, stream>>>(
        ffbf, w2T, 8192, 512, 2048, tmp, mid, (void*)(b2 + (size_t)l * 512),
        nullptr, nullptr, nullptr);

    ln_kernel<<<dim3(2048), blk, 0, stream>>>(
        tmp, 0, ff_g + l * 512, ff_b + l * 512, hcur, Xbf,
        out + (size_t)(2 + l) * BTD, (l == 3) ? out : (float*)nullptr);
  }
}

// Round 7
// 993.123 us; speedup vs baseline: 1.0394x; 1.0394x over previous
//
#include <hip/hip_runtime.h>
#include <cstddef>

// ---------------------------------------------------------------------------
// TransformerXL forward on gfx950.  T=512 B=16 D=512 H=8 DH=64 DI=2048 L=4.
// All matmuls bf16 MFMA (16x16x32), fp32 accum. LN / softmax fp32.
// ---------------------------------------------------------------------------

typedef unsigned short u16;
typedef short s16x8 __attribute__((ext_vector_type(8)));
typedef unsigned short u16x8 __attribute__((ext_vector_type(8)));
typedef float f32x4 __attribute__((ext_vector_type(4)));

__device__ __forceinline__ u16 f2bf(float f) {  // RNE float->bf16
  unsigned int u = __float_as_uint(f);
  u += 0x7fffu + ((u >> 16) & 1u);
  return (u16)(u >> 16);
}
__device__ __forceinline__ float bf2f(u16 u) {
  return __uint_as_float((unsigned int)u << 16);
}

__device__ __forceinline__ f32x4 mfma16(s16x8 a, s16x8 b, f32x4 c) {
  return __builtin_amdgcn_mfma_f32_16x16x32_bf16(a, b, c, 0, 0, 0);
}

__device__ __forceinline__ void gl2lds16(const u16* g, u16* l) {
  __builtin_amdgcn_global_load_lds(
      (const __attribute__((address_space(1))) unsigned int*)g,
      (__attribute__((address_space(3))) unsigned int*)l, 16, 0, 0);
}

#define FENCE_BAR()                                         \
  do {                                                      \
    asm volatile("s_waitcnt lgkmcnt(0)" ::: "memory");      \
    __builtin_amdgcn_s_barrier();                           \
    __builtin_amdgcn_sched_barrier(0);                      \
  } while (0)

// ---------------------------------------------------------------------------
// Generic bf16 GEMM: C(M,N) = A(M,K) * Bt(N,K)^T ; 128xTN tile, BK=64,
// 256 threads = 4 waves in 2x2. TN=128 or 64 (64 doubles grid for small N).
// XOR chunk swizzle (chunk ^= row&7) on the 64-u16-row LDS tiles, computed on
// the per-lane GLOBAL address (LDS dest lane-contiguous per gl2lds contract).
//
// REG-PREFETCH PIPELINE (attn-proven, rounds 5/6): LDS stays SINGLE-buffered
// (32 KB TN=128 / 24 KB TN=64 -> occupancy preserved, unlike the round-6
// 64 KB LDS double-buffer which halved blocks/CU and regressed). During
// compute of tile kt, the 6-8 16B/lane global loads for tile kt+1 are in
// flight into registers (+24/32 VGPR, ~145 total -> still 3 waves/SIMD,
// default launch bounds so NO allocator clamp/spill - round-3 lesson).
// At the top of iter kt+1 they are ds_written to the same LDS addresses
// gl2lds used. Barriers: lgkmcnt(0)+s_barrier only; NO vmcnt(0) in the main
// loop (the commit's ds_writes get a compiler-inserted vmcnt wait on the
// prefetch regs, which had the whole 32-MFMA compute phase to land).
// Prologue: tile 0 via gl2lds, then issue prefetch(1), then counted
// vmcnt(4+NBQ) = waits the gl2lds set only.
//
// MODE 0: rk epilogue, ALL LAYERS batched: blockIdx.z = layer*2+group;
//         A = r_bf (+group), Bt = rnetT base (+layer), p0 = rkb bf16
//         [layer][group][head][1024][64].
// MODE 1: qkv split    -> Qw(+rwb) Qr(+rrb) Kb Vb bf16 (p0..p3,p4,p5)
// MODE 2: + residual   -> f32 p0 = C + p1
// MODE 3: + res + bias -> f32 p0 = C + p1 + bias(p2)
// MODE 4: bias + relu  -> bf16 p0 = relu(C + bias(p1))
// ---------------------------------------------------------------------------
template <int MODE, int TN>
__launch_bounds__(256) __global__
void gemm_bt(const u16* __restrict__ A, const u16* __restrict__ Bt,
             int M, int N, int K,
             void* p0, void* p1, void* p2, void* p3,
             const float* __restrict__ p4, const float* __restrict__ p5) {
  (void)M;
  constexpr int NT = TN / 32;   // n-tiles (16 wide) per wave
  constexpr int NBQ = TN / 32;  // B staging instrs per wave (4 or 2)
  __shared__ u16 As[8192];
  __shared__ u16 Bs[TN * 64];
  const int tid = threadIdx.x;
  const int lane = tid & 63;
  const int w = tid >> 6;
  const int quad = lane >> 4, l15 = lane & 15;
  const int m0 = blockIdx.y << 7, n0 = blockIdx.x * TN;

  if constexpr (MODE == 0) {
    const int lz = blockIdx.z >> 1, gz = blockIdx.z & 1;
    A += (size_t)gz * 524288;          // group offset in r_bf
    Bt += (size_t)lz * 262144;         // per-layer rnetT
    p0 = (void*)((u16*)p0 + (size_t)lz * 1048576 + (size_t)gz * 524288);
  }

  f32x4 acc[4][NT];
#pragma unroll
  for (int a = 0; a < 4; ++a)
#pragma unroll
    for (int b = 0; b < NT; ++b) {
      f32x4 z = {0.f, 0.f, 0.f, 0.f};
      acc[a][b] = z;
    }

  // Staging geometry: per instr, wave w covers 8 rows (8 x 64 u16 = 1 KB).
  const int rg = lane >> 3;
  const int cz = ((lane & 7) ^ rg) << 3;  // swizzled u16 col offset
  const u16* gA = A + (size_t)(m0 + w * 8 + rg) * K + cz;
  const u16* gB = Bt + (size_t)(n0 + w * 8 + rg) * K + cz;
  u16* lA = &As[w * 512];
  u16* lB = &Bs[w * 512];

  const int wm = (w >> 1) << 6, wn = (w & 1) * (NT * 16);
  const int rsw = l15 & 7;  // fragment row&7 (wm, t*16 are multiples of 8)
  const int nk = K >> 6;

  // Prefetch registers for tile kt+1.
  s16x8 pA[4], pB[NBQ];
  auto prefetch = [&](int kt) {
    const int k0 = kt << 6;
#pragma unroll
    for (int q = 0; q < 4; ++q)
      pA[q] = *(const s16x8*)(gA + (size_t)(q * 32) * K + k0);
#pragma unroll
    for (int q = 0; q < NBQ; ++q)
      pB[q] = *(const s16x8*)(gB + (size_t)(q * 32) * K + k0);
  };

  // Prologue: tile 0 via gl2lds, then issue prefetch(1), counted vmcnt.
#pragma unroll
  for (int q = 0; q < 4; ++q)
    gl2lds16(gA + (size_t)(q * 32) * K, lA + q * 2048);
#pragma unroll
  for (int q = 0; q < NBQ; ++q)
    gl2lds16(gB + (size_t)(q * 32) * K, lB + q * 2048);
  asm volatile("" ::: "memory");  // pin: gl2lds issued before prefetch
  __builtin_amdgcn_sched_barrier(0);
  if (nk > 1) {
    prefetch(1);
    if constexpr (NBQ == 4)
      asm volatile("s_waitcnt vmcnt(8)" ::: "memory");  // 8 gl2lds done
    else
      asm volatile("s_waitcnt vmcnt(6)" ::: "memory");  // 6 gl2lds done
  } else {
    asm volatile("s_waitcnt vmcnt(0)" ::: "memory");
  }
  __builtin_amdgcn_s_barrier();
  __builtin_amdgcn_sched_barrier(0);

  for (int kt = 0; kt < nk; ++kt) {
    if (kt > 0) {
      // All waves consumed buffer for kt-1 (ds_reads drained by lgkm+bar).
      FENCE_BAR();
      // Commit prefetched tile kt (same addresses gl2lds used); compiler
      // auto-waits vmcnt on the prefetch regs (landed during compute).
#pragma unroll
      for (int q = 0; q < 4; ++q)
        *(s16x8*)(lA + q * 2048 + lane * 8) = pA[q];
#pragma unroll
      for (int q = 0; q < NBQ; ++q)
        *(s16x8*)(lB + q * 2048 + lane * 8) = pB[q];
      if (kt + 1 < nk) prefetch(kt + 1);
      FENCE_BAR();  // ds_writes visible; next-tile loads stay in flight
    }
#pragma unroll
    for (int ks = 0; ks < 2; ++ks) {
      // global chunk g = ks*4+quad of row r lives at LDS chunk g ^ (r&7)
      const int co = ((ks * 4 + quad) ^ rsw) << 3;
      s16x8 af[4], bfg[NT];
#pragma unroll
      for (int t = 0; t < 4; ++t)
        af[t] = *(const s16x8*)&As[(wm + t * 16 + l15) * 64 + co];
#pragma unroll
      for (int t = 0; t < NT; ++t)
        bfg[t] = *(const s16x8*)&Bs[(wn + t * 16 + l15) * 64 + co];
#pragma unroll
      for (int mt = 0; mt < 4; ++mt)
#pragma unroll
        for (int nt = 0; nt < NT; ++nt)
          acc[mt][nt] = mfma16(af[mt], bfg[nt], acc[mt][nt]);
    }
  }

#pragma unroll
  for (int mt = 0; mt < 4; ++mt) {
#pragma unroll
    for (int nt = 0; nt < NT; ++nt) {
#pragma unroll
      for (int r = 0; r < 4; ++r) {
        const int row = m0 + wm + mt * 16 + quad * 4 + r;
        const int col = n0 + wn + nt * 16 + l15;
        const float v = acc[mt][nt][r];
        if constexpr (MODE == 0) {
          const int hn = col >> 6, d = col & 63;
          ((u16*)p0)[((size_t)hn * 1024 + row) * 64 + d] = f2bf(v);
        } else if constexpr (MODE == 1) {
          const int i = row >> 4, b = row & 15;
          const int which = col >> 9, hn = (col >> 6) & 7, d = col & 63;
          const int bn = b * 8 + hn;
          const size_t idx = ((size_t)bn * 512 + i) * 64 + d;
          if (which == 0) {
            ((u16*)p0)[idx] = f2bf(v + p4[hn * 64 + d]);
            ((u16*)p1)[idx] = f2bf(v + p5[hn * 64 + d]);
          } else if (which == 1) {
            ((u16*)p2)[idx] = f2bf(v);
          } else {
            ((u16*)p3)[idx] = f2bf(v);
          }
        } else if constexpr (MODE == 2) {
          ((float*)p0)[(size_t)row * N + col] =
              v + ((const float*)p1)[(size_t)row * N + col];
        } else if constexpr (MODE == 3) {
          ((float*)p0)[(size_t)row * N + col] =
              v + ((const float*)p1)[(size_t)row * N + col] +
              ((const float*)p2)[col];
        } else {
          float t = v + ((const float*)p1)[col];
          ((u16*)p0)[(size_t)row * N + col] = f2bf(t > 0.f ? t : 0.f);
        }
      }
    }
  }
}

// ---------------------------------------------------------------------------
// Weight transpose+convert: src f32 (R,C) -> dst bf16 (C,R). 64x64 tiles.
// ---------------------------------------------------------------------------
__launch_bounds__(256) __global__
void transpose_w_kernel(const float* __restrict__ qkv, const float* __restrict__ rnet,
                        const float* __restrict__ ow, const float* __restrict__ w1,
                        const float* __restrict__ w2, u16* __restrict__ dst) {
  const int type = blockIdx.z, l = blockIdx.y, tile = blockIdx.x;
  int R, C;
  const float* src;
  u16* out;
  switch (type) {
    case 0: R = 512; C = 1536; src = qkv + (size_t)l * 786432; out = dst + (size_t)l * 786432; break;
    case 1: R = 512; C = 512;  src = rnet + (size_t)l * 262144; out = dst + 3145728 + (size_t)l * 262144; break;
    case 2: R = 512; C = 512;  src = ow + (size_t)l * 262144;   out = dst + 4194304 + (size_t)l * 262144; break;
    case 3: R = 512; C = 2048; src = w1 + (size_t)l * 1048576;  out = dst + 5242880 + (size_t)l * 1048576; break;
    default: R = 2048; C = 512; src = w2 + (size_t)l * 1048576; out = dst + 9437184 + (size_t)l * 1048576; break;
  }
  const int tC = C >> 6;
  const int tR = R >> 6;
  if (tile >= tC * tR) return;
  const int r0 = (tile / tC) << 6, c0 = (tile % tC) << 6;
  __shared__ float tb[64][65];
  const int tid = threadIdx.x;
  const int rr = tid >> 2, cc = (tid & 3) << 4;
#pragma unroll
  for (int j = 0; j < 4; ++j) {
    f32x4 u = *(const f32x4*)(src + (size_t)(r0 + rr) * C + c0 + cc + j * 4);
    tb[rr][cc + j * 4 + 0] = u[0];
    tb[rr][cc + j * 4 + 1] = u[1];
    tb[rr][cc + j * 4 + 2] = u[2];
    tb[rr][cc + j * 4 + 3] = u[3];
  }
  __syncthreads();
  u16x8 o0, o1;
#pragma unroll
  for (int j = 0; j < 8; ++j) o0[j] = f2bf(tb[cc + j][rr]);
#pragma unroll
  for (int j = 0; j < 8; ++j) o1[j] = f2bf(tb[cc + 8 + j][rr]);
  *(u16x8*)(out + (size_t)(c0 + rr) * R + r0 + cc) = o0;
  *(u16x8*)(out + (size_t)(c0 + rr) * R + r0 + cc + 8) = o1;
}

// ---------------------------------------------------------------------------
// Positional embeddings: r_bf[g][j][d], g=0 fw (pos=512-j), g=1 bw (pos=j-512)
// ---------------------------------------------------------------------------
__launch_bounds__(256) __global__
void posemb_kernel(u16* __restrict__ r_bf) {
  const int idx = blockIdx.x * 256 + threadIdx.x;  // 2*1024*512
  const int d = idx & 511, j = (idx >> 9) & 1023, g = idx >> 19;
  const float pos = g ? (float)(j - 512) : (float)(512 - j);
  const int dp = d & 255;
  const float invf = expf((float)dp * (-9.210340371976184f / 256.f));
  const float v = pos * invf;
  r_bf[idx] = f2bf((d < 256) ? sinf(v) : cosf(v));
}

// ---------------------------------------------------------------------------
// V transpose per layer: Vb[bn][j][d] -> Vt[bn][d][j] (bf16), 64-key tiles.
// ---------------------------------------------------------------------------
__launch_bounds__(256) __global__
void transpose_v_kernel(const u16* __restrict__ Vb, u16* __restrict__ Vt) {
  const int bn = blockIdx.y, j0 = blockIdx.x << 6;
  __shared__ u16 tb[64][72];
  const int tid = threadIdx.x;
#pragma unroll
  for (int q = 0; q < 2; ++q) {
    const int s = q * 256 + tid;
    const int jj = s >> 3, c = s & 7;
    u16x8 u = *(const u16x8*)(Vb + ((size_t)bn * 512 + j0 + jj) * 64 + c * 8);
    *(u16x8*)&tb[jj][c * 8] = u;
  }
  __syncthreads();
#pragma unroll
  for (int q = 0; q < 2; ++q) {
    const int s = q * 256 + tid;
    const int d = s >> 3, c = s & 7;
    u16x8 o;
#pragma unroll
    for (int e = 0; e < 8; ++e) o[e] = tb[c * 8 + e][d];
    *(u16x8*)(Vt + ((size_t)bn * 64 + d) * 512 + j0 + c * 8) = o;
  }
}

// ---------------------------------------------------------------------------
// Fused rel-attention, flash-style. Block = one (b,head) x 64 queries; 4 waves.
// LDS = 40960 B -> 4 blocks/CU. Grid (bn, i0): the 8 i0-blocks sharing one
// (b,head)'s K/V/rk get ids === bn (mod 8) -> same XCD -> fetched once, L2-hot.
// PIPELINED (T14 + counted waits), proven rounds 5/6. Unchanged.
// ---------------------------------------------------------------------------
__launch_bounds__(256) __global__
void attn_kernel(const u16* __restrict__ Qw, const u16* __restrict__ Qr,
                 const u16* __restrict__ Kb, const u16* __restrict__ Vt,
                 const u16* __restrict__ rkb, const int* __restrict__ smask,
                 u16* __restrict__ vecb) {
  __shared__ u16 Ks[4096];    // [key][d]   64x64, swizzled
  __shared__ u16 Vts[4096];   // [d][key]   64x64, swizzled
  __shared__ u16 Band[8192];  // [band][d] 128x64, swizzled, 64-row ring
  __shared__ u16 Ps[4096];    // per wave [16][64], XOR-chunk swizzled

  const int tid = threadIdx.x, lane = tid & 63, w = tid >> 6;
  const int quad = lane >> 4, l15 = lane & 15;
  const int bn = blockIdx.x, b = bn >> 3, n = bn & 7;
  const int g = (b >= 8) ? 1 : 0;
  const int i0 = blockIdx.y << 6;

  // Per-thread mask bits: bit s (s=0..31) = smask[b*512 + s*16 + l15] != 0.
  unsigned mbits = 0;
  const int* smb = smask + b * 512 + l15;
#pragma unroll
  for (int s = 0; s < 32; ++s)
    if (smb[s * 16]) mbits |= 1u << s;
  // Wave-uniform valid-tile mask (identical across all 4 waves).
  unsigned vmask = 0;
#pragma unroll
  for (int jt = 0; jt < 8; ++jt)
    if (__any((int)((mbits >> (jt * 4)) & 15u))) vmask |= 1u << jt;
  const int ntiles = vmask ? (32 - __clz((int)vmask)) : 0;

  const u16* qwp = Qw + ((size_t)bn * 512 + i0 + w * 16 + l15) * 64 + quad * 8;
  const u16* qrp = Qr + ((size_t)bn * 512 + i0 + w * 16 + l15) * 64 + quad * 8;
  const s16x8 qw0 = *(const s16x8*)qwp, qw1 = *(const s16x8*)(qwp + 32);
  const s16x8 qr0 = *(const s16x8*)qrp, qr1 = *(const s16x8*)(qrp + 32);

  const u16* kbase = Kb + (size_t)bn * (512 * 64);
  const u16* vbase = Vt + (size_t)bn * (64 * 512);
  const u16* rkg = rkb + (size_t)(g * 8 + n) * (1024 * 64);

  const int s0 = w * 64 + lane;
  const int rl = s0 >> 3;                   // LDS row within 32-row instr
  const int cd = ((s0 & 7) ^ (rl & 7)) * 8; // swizzled data chunk (u16 offset)
  u16* lK0 = &Ks[w * 512];
  u16* lK1 = &Ks[(4 + w) * 512];
  u16* lV0 = &Vts[w * 512];
  u16* lV1 = &Vts[(4 + w) * 512];
  u16* lBq[4] = {&Band[w * 512], &Band[(4 + w) * 512], &Band[(8 + w) * 512],
                 &Band[(12 + w) * 512]};
  u16* pwv = &Ps[w * 1024];

  // fragment-read swizzle: chunk quad -> quad ^ (row&7); row&7 == l15&7 here
  const int sw8 = ((quad ^ (l15 & 7)) * 8);
  const int sw8b = (((quad ^ (l15 & 7)) ^ 4) * 8);

  // rel-shift gather lanes: dest (quad,l15,r) needs band element at
  // k = 15 + nj - mi (nj = t*16+l15, mi = quad*4+r). With e = 15+l15-mi:
  // source tile = t + (e>>4), source lane = quad*16 + (e&15), reg = r.
  int sl[4], hisel[4];
#pragma unroll
  for (int r = 0; r < 4; ++r) {
    const int e = 15 + l15 - quad * 4 - r;
    sl[r] = (quad << 4) | (e & 15);
    hisel[r] = e >> 4;
  }

  f32x4 O[4];
  float m_st[4], l_st[4];
#pragma unroll
  for (int t = 0; t < 4; ++t) {
    f32x4 z = {0.f, 0.f, 0.f, 0.f};
    O[t] = z;
    m_st[t] = -1e30f;
    l_st[t] = 0.f;
  }

  // Prefetch registers for tile jt+1 (K hi/lo, V hi/lo, Band new-64-rows).
  s16x8 rK0, rK1, rV0, rV1, rB0, rB1;
  auto issue_prefetch = [&](int nt) {  // nt = tile index being prefetched
    const int j0n = nt << 6;
    const int jr0n = 449 + j0n - i0;
    rK0 = *(const s16x8*)(kbase + (size_t)(j0n + rl) * 64 + cd);
    rK1 = *(const s16x8*)(kbase + (size_t)(j0n + 32 + rl) * 64 + cd);
    rV0 = *(const s16x8*)(vbase + (size_t)rl * 512 + j0n + cd);
    rV1 = *(const s16x8*)(vbase + (size_t)(rl + 32) * 512 + j0n + cd);
    int rr0 = jr0n + 64 + rl;
    int rr1 = jr0n + 96 + rl;
    rr0 = rr0 < 1023 ? rr0 : 1023;  // last band row unused; avoid OOB
    rr1 = rr1 < 1023 ? rr1 : 1023;
    rB0 = *(const s16x8*)(rkg + (size_t)rr0 * 64 + cd);
    rB1 = *(const s16x8*)(rkg + (size_t)rr1 * 64 + cd);
  };

  for (int jt = 0; jt < ntiles; ++jt) {
    if (jt == 0) {
      // Full stage of tile 0 via gl2lds (no extra registers), then issue
      // tile-1 prefetch, then counted vmcnt: waits the 8 gl2lds only.
      const int jr00 = 449 - i0;
      gl2lds16(kbase + (size_t)rl * 64 + cd, lK0);
      gl2lds16(kbase + (size_t)(32 + rl) * 64 + cd, lK1);
      gl2lds16(vbase + (size_t)rl * 512 + cd, lV0);
      gl2lds16(vbase + (size_t)(rl + 32) * 512 + cd, lV1);
#pragma unroll
      for (int q = 0; q < 4; ++q) {
        int rrow = jr00 + q * 32 + rl;
        rrow = rrow < 1023 ? rrow : 1023;
        gl2lds16(rkg + (size_t)rrow * 64 + cd, lBq[q]);
      }
      asm volatile("" ::: "memory");  // pin: gl2lds issued before prefetch
      __builtin_amdgcn_sched_barrier(0);
      if (ntiles > 1) {
        issue_prefetch(1);
        asm volatile("s_waitcnt vmcnt(6)" ::: "memory");  // 8 gl2lds done
      } else {
        asm volatile("s_waitcnt vmcnt(0)" ::: "memory");
      }
      __builtin_amdgcn_s_barrier();
      __builtin_amdgcn_sched_barrier(0);
    } else {
      // All waves finished reading LDS for jt-1 (every ds_read was consumed
      // by an MFMA before this point).
      FENCE_BAR();
      // Commit prefetched tile jt to LDS (same addresses gl2lds used).
      *(s16x8*)(lK0 + lane * 8) = rK0;
      *(s16x8*)(lK1 + lane * 8) = rK1;
      *(s16x8*)(lV0 + lane * 8) = rV0;
      *(s16x8*)(lV1 + lane * 8) = rV1;
      const int segb = ((jt + 1) & 1) << 1;  // ring segments for new rows
      *(s16x8*)(lBq[segb] + lane * 8) = rB0;
      *(s16x8*)(lBq[segb + 1] + lane * 8) = rB1;
      if (jt + 1 < ntiles) issue_prefetch(jt + 1);
      FENCE_BAR();  // lgkmcnt(0): ds_writes visible; loads stay in flight
    }

    // AC = (q+rwb) . K^T
    f32x4 ac[4];
#pragma unroll
    for (int t = 0; t < 4; ++t) {
      f32x4 z = {0.f, 0.f, 0.f, 0.f};
      ac[t] = z;
      s16x8 k0f = *(const s16x8*)&Ks[(t * 16 + l15) * 64 + sw8];
      s16x8 k1f = *(const s16x8*)&Ks[(t * 16 + l15) * 64 + sw8b];
      ac[t] = mfma16(qw0, k0f, ac[t]);
      ac[t] = mfma16(qw1, k1f, ac[t]);
    }
    // BD band: wave w covers band rows [48-16w, 128-16w), ring-offset reads
    const int bb0 = 48 - w * 16;
    const int rofs = (jt & 1) << 6;
    f32x4 bd[5];
#pragma unroll
    for (int t = 0; t < 5; ++t) {
      f32x4 z = {0.f, 0.f, 0.f, 0.f};
      const int prow = ((bb0 + t * 16 + l15) + rofs) & 127;
      s16x8 b0f = *(const s16x8*)&Band[prow * 64 + sw8];
      s16x8 b1f = *(const s16x8*)&Band[prow * 64 + sw8b];
      bd[t] = mfma16(qr1, b1f, mfma16(qr0, b0f, z));
    }
    // rel-shift via in-quad bpermute; sh[t] doubles as hi of tile t-1
    float sh[5][4];
#pragma unroll
    for (int t = 0; t < 5; ++t)
#pragma unroll
      for (int r = 0; r < 4; ++r) sh[t][r] = __shfl(bd[t][r], sl[r]);

    // combine + scale + mask
    float pv[4][4];
#pragma unroll
    for (int t = 0; t < 4; ++t) {
      const float mk = ((mbits >> (jt * 4 + t)) & 1u) ? 0.f : -1e9f;
#pragma unroll
      for (int r = 0; r < 4; ++r) {
        const float bdv = hisel[r] ? sh[t + 1][r] : sh[t][r];
        pv[t][r] = (ac[t][r] + bdv) * 0.125f + mk;
      }
    }
    // online softmax per C-row (16-lane butterfly within l15 group)
#pragma unroll
    for (int r = 0; r < 4; ++r) {
      float mx = fmaxf(fmaxf(pv[0][r], pv[1][r]), fmaxf(pv[2][r], pv[3][r]));
#pragma unroll
      for (int xm = 1; xm < 16; xm <<= 1) mx = fmaxf(mx, __shfl_xor(mx, xm));
      const float mn = fmaxf(m_st[r], mx);
      const float al = __expf(m_st[r] - mn);
      m_st[r] = mn;
      float rs = 0.f;
#pragma unroll
      for (int t = 0; t < 4; ++t) {
        pv[t][r] = __expf(pv[t][r] - mn);
        rs += pv[t][r];
      }
#pragma unroll
      for (int xm = 1; xm < 16; xm <<= 1) rs += __shfl_xor(rs, xm);
      l_st[r] = l_st[r] * al + rs;
#pragma unroll
      for (int t = 0; t < 4; ++t) O[t][r] *= al;
    }
    // P -> LDS ([16][64] XOR-chunk swizzled), PV MFMA. Ps is per-wave
    // private, so same-wave DS ordering makes this race-free.
#pragma unroll
    for (int t = 0; t < 4; ++t)
#pragma unroll
      for (int r = 0; r < 4; ++r) {
        const int row = quad * 4 + r, col = t * 16 + l15;
        pwv[row * 64 + ((((col >> 3) ^ row) & 7) << 3) + (col & 7)] =
            f2bf(pv[t][r]);
      }
#pragma unroll
    for (int ks = 0; ks < 2; ++ks) {
      const int ch = (((ks * 4 + quad) ^ l15) & 7) << 3;
      s16x8 pf = *(const s16x8*)&pwv[l15 * 64 + ch];
#pragma unroll
      for (int td = 0; td < 4; ++td) {
        s16x8 vf = *(const s16x8*)&Vts[(td * 16 + l15) * 64 +
                                       (ks == 0 ? sw8 : sw8b)];
        O[td] = mfma16(pf, vf, O[td]);
      }
    }
  }

#pragma unroll
  for (int td = 0; td < 4; ++td) {
#pragma unroll
    for (int r = 0; r < 4; ++r) {
      const int i = i0 + w * 16 + quad * 4 + r;
      const float val = O[td][r] / l_st[r];
      vecb[((size_t)i * 16 + b) * 512 + n * 64 + td * 16 + l15] = f2bf(val);
    }
  }
}

// ---------------------------------------------------------------------------
// LayerNorm over D=512, 1 wave per row. row = i*B+b. Optional outputs:
// dst32 f32 (T,B,D), dstbf bf16 (T,B,D), o1/o2 f32 (B,T,D) (for d_out).
// ---------------------------------------------------------------------------
__launch_bounds__(256) __global__
void ln_kernel(const float* __restrict__ src, int src_is_bt,
               const float* __restrict__ gw, const float* __restrict__ bww,
               float* __restrict__ dst32, u16* __restrict__ dstbf,
               float* __restrict__ o1, float* __restrict__ o2) {
  const int row = blockIdx.x * 4 + (threadIdx.x >> 6);
  const int lane = threadIdx.x & 63;
  const int i = row >> 4, b = row & 15;
  const float* x = src + (src_is_bt ? ((size_t)b * 512 + i) * 512 : (size_t)row * 512);
  f32x4 u0 = *(const f32x4*)(x + lane * 8);
  f32x4 u1 = *(const f32x4*)(x + lane * 8 + 4);
  float s = u0[0] + u0[1] + u0[2] + u0[3] + u1[0] + u1[1] + u1[2] + u1[3];
  float sq = u0[0] * u0[0] + u0[1] * u0[1] + u0[2] * u0[2] + u0[3] * u0[3] +
             u1[0] * u1[0] + u1[1] * u1[1] + u1[2] * u1[2] + u1[3] * u1[3];
  for (int m = 1; m < 64; m <<= 1) {
    s += __shfl_xor(s, m);
    sq += __shfl_xor(sq, m);
  }
  const float mean = s * (1.f / 512.f);
  const float var = sq * (1.f / 512.f) - mean * mean;
  const float rs = rsqrtf(var + 1e-6f);
  f32x4 g0 = *(const f32x4*)(gw + lane * 8);
  f32x4 g1 = *(const f32x4*)(gw + lane * 8 + 4);
  f32x4 b0 = *(const f32x4*)(bww + lane * 8);
  f32x4 b1 = *(const f32x4*)(bww + lane * 8 + 4);
  f32x4 y0, y1;
#pragma unroll
  for (int k = 0; k < 4; ++k) {
    y0[k] = (u0[k] - mean) * rs * g0[k] + b0[k];
    y1[k] = (u1[k] - mean) * rs * g1[k] + b1[k];
  }
  const size_t o_ib = (size_t)row * 512 + lane * 8;
  const size_t o_tb = ((size_t)b * 512 + i) * 512 + lane * 8;
  if (dst32) {
    *(f32x4*)(dst32 + o_ib) = y0;
    *(f32x4*)(dst32 + o_ib + 4) = y1;
  }
  if (dstbf) {
    u16x8 ov;
#pragma unroll
    for (int k = 0; k < 4; ++k) {
      ov[k] = f2bf(y0[k]);
      ov[k + 4] = f2bf(y1[k]);
    }
    *(u16x8*)(dstbf + o_ib) = ov;
  }
  if (o1) {
    *(f32x4*)(o1 + o_tb) = y0;
    *(f32x4*)(o1 + o_tb + 4) = y1;
  }
  if (o2) {
    *(f32x4*)(o2 + o_tb) = y0;
    *(f32x4*)(o2 + o_tb + 4) = y1;
  }
}

// ---------------------------------------------------------------------------
extern "C" void kernel_launch(void* const* d_in, const int* in_sizes, int n_in,
                              void* d_out, int out_size, void* d_ws, size_t ws_size,
                              hipStream_t stream) {
  (void)in_sizes; (void)n_in; (void)out_size; (void)ws_size;
  const float* h_in = (const float*)d_in[0];
  const int* smask = (const int*)d_in[1];  // bool -> int32 per harness contract
  const float* rwb = (const float*)d_in[2];
  const float* rrb = (const float*)d_in[3];
  const float* top_g = (const float*)d_in[4];
  const float* top_b = (const float*)d_in[5];
  const float* qkv_w = (const float*)d_in[6];
  const float* rnet_w = (const float*)d_in[7];
  const float* o_w = (const float*)d_in[8];
  const float* attn_g = (const float*)d_in[9];
  const float* attn_b = (const float*)d_in[10];
  const float* w1 = (const float*)d_in[11];
  const float* b1 = (const float*)d_in[12];
  const float* w2 = (const float*)d_in[13];
  const float* b2 = (const float*)d_in[14];
  const float* ff_g = (const float*)d_in[15];
  const float* ff_b = (const float*)d_in[16];
  float* out = (float*)d_out;
  const size_t BTD = 4194304;  // 16*512*512

  char* ws = (char*)d_ws;
  size_t off = 0;
  auto alloc = [&](size_t bytes) {
    void* p = ws + off;
    off += (bytes + 255) & ~(size_t)255;
    return p;
  };
  u16* wT = (u16*)alloc(13631488ull * 2);       // transposed bf16 weights
  u16* r_bf = (u16*)alloc(2ull * 1024 * 512 * 2);
  u16* rkb = (u16*)alloc(8ull << 20);           // 4 layers x 2 groups x 8 x 1024 x 64 bf16
  u16* Qw = (u16*)alloc(8ull << 20);
  u16* Qr = (u16*)alloc(8ull << 20);
  u16* Kb = (u16*)alloc(8ull << 20);
  u16* Vt = (u16*)alloc(8ull << 20);
  u16* vecb = (u16*)alloc(8ull << 20);
  u16* Xbf = (u16*)alloc(8ull << 20);
  u16* ffbf = (u16*)alloc(32ull << 20);
  float* hcur = (float*)alloc(16ull << 20);
  // aliases (lifetimes verified): tmp over Qw+Qr, mid over Kb+Vt, Vb over ffbf[0:8MB]
  float* tmp = (float*)Qw;
  float* mid = (float*)Kb;
  u16* Vb = ffbf;

  dim3 blk(256);
  transpose_w_kernel<<<dim3(256, 4, 5), blk, 0, stream>>>(qkv_w, rnet_w, o_w, w1, w2, wT);
  posemb_kernel<<<dim3(4096), blk, 0, stream>>>(r_bf);
  ln_kernel<<<dim3(2048), blk, 0, stream>>>(h_in, 1, top_g, top_b, hcur, Xbf,
                                            out + BTD, (float*)nullptr);

  // All 4 layers' rk GEMMs batched (activation-independent): z = layer*2+group
  gemm_bt<0, 64><<<dim3(8, 8, 8), blk, 0, stream>>>(
      r_bf, wT + 3145728, 1024, 512, 512,
      rkb, nullptr, nullptr, nullptr, nullptr, nullptr);

  for (int l = 0; l < 4; ++l) {
    u16* qkvT = wT + (size_t)l * 786432;
    u16* oT = wT + 4194304 + (size_t)l * 262144;
    u16* w1T = wT + 5242880 + (size_t)l * 1048576;
    u16* w2T = wT + 9437184 + (size_t)l * 1048576;

    gemm_bt<1, 128><<<dim3(12, 64), blk, 0, stream>>>(
        Xbf, qkvT, 8192, 1536, 512, Qw, Qr, Kb, Vb, rwb, rrb);

    transpose_v_kernel<<<dim3(8, 128), blk, 0, stream>>>(Vb, Vt);

    attn_kernel<<<dim3(128, 8), blk, 0, stream>>>(
        Qw, Qr, Kb, Vt, rkb + (size_t)l * 1048576, smask, vecb);

    gemm_bt<2, 64><<<dim3(8, 64), blk, 0, stream>>>(
        vecb, oT, 8192, 512, 512, tmp, hcur, nullptr, nullptr, nullptr, nullptr);

    ln_kernel<<<dim3(2048), blk, 0, stream>>>(tmp, 0, attn_g + l * 512, attn_b + l * 512,
                                              mid, Xbf, (float*)nullptr, (float*)nullptr);

    gemm_bt<4, 128><<<dim3(16, 64), blk, 0, stream>>>(
        Xbf, w1T, 8192, 2048, 512, ffbf, (void*)(b1 + (size_t)l * 2048),
        nullptr, nullptr, nullptr, nullptr);

    gemm_bt<3, 64><<<dim3(8, 64), blk, 0, stream>>>(
        ffbf, w2T, 8192, 512, 2048, tmp, mid, (void*)(b2 + (size_t)l * 512),
        nullptr, nullptr, nullptr);

    ln_kernel<<<dim3(2048), blk, 0, stream>>>(
        tmp, 0, ff_g + l * 512, ff_b + l * 512, hcur, Xbf,
        out + (size_t)(2 + l) * BTD, (l == 3) ? out : (float*)nullptr);
  }
}

// Round 8
// 987.836 us; speedup vs baseline: 1.0449x; 1.0054x over previous
//
#include <hip/hip_runtime.h>
#include <cstddef>

// ---------------------------------------------------------------------------
// TransformerXL forward on gfx950.  T=512 B=16 D=512 H=8 DH=64 DI=2048 L=4.
// All matmuls bf16 MFMA (16x16x32), fp32 accum. LN / softmax fp32.
// ---------------------------------------------------------------------------

typedef unsigned short u16;
typedef short s16x8 __attribute__((ext_vector_type(8)));
typedef unsigned short u16x8 __attribute__((ext_vector_type(8)));
typedef float f32x4 __attribute__((ext_vector_type(4)));

__device__ __forceinline__ u16 f2bf(float f) {  // RNE float->bf16
  unsigned int u = __float_as_uint(f);
  u += 0x7fffu + ((u >> 16) & 1u);
  return (u16)(u >> 16);
}
__device__ __forceinline__ float bf2f(u16 u) {
  return __uint_as_float((unsigned int)u << 16);
}

__device__ __forceinline__ f32x4 mfma16(s16x8 a, s16x8 b, f32x4 c) {
  return __builtin_amdgcn_mfma_f32_16x16x32_bf16(a, b, c, 0, 0, 0);
}

__device__ __forceinline__ void gl2lds16(const u16* g, u16* l) {
  __builtin_amdgcn_global_load_lds(
      (const __attribute__((address_space(1))) unsigned int*)g,
      (__attribute__((address_space(3))) unsigned int*)l, 16, 0, 0);
}

#define FENCE_BAR()                                         \
  do {                                                      \
    asm volatile("s_waitcnt lgkmcnt(0)" ::: "memory");      \
    __builtin_amdgcn_s_barrier();                           \
    __builtin_amdgcn_sched_barrier(0);                      \
  } while (0)

// ---------------------------------------------------------------------------
// Generic bf16 GEMM: C(M,N) = A(M,K) * Bt(N,K)^T ; 128xTN tile, BK=64,
// 256 threads = 4 waves in 2x2. TN=64 everywhere now (round-8): the TN=128
// variant's register budget (acc 64 + prefetch 32 + frags 32 + addr ~ 160
// VGPR) lands in the 129-256 band -> 8 waves/CU = 2 blocks/CU, which starves
// the latency-hiding the reg-prefetch pipeline needs. TN=64 (~115 VGPR,
// 24 KB LDS) sits in the <=128 band -> 16 waves/CU = 4 blocks/CU.
// XOR chunk swizzle (chunk ^= row&7) on the 64-u16-row LDS tiles, computed on
// the per-lane GLOBAL address (LDS dest lane-contiguous per gl2lds contract).
//
// REG-PREFETCH PIPELINE (attn-proven, rounds 5/7): LDS single-buffered.
// During compute of tile kt, the 6 16B/lane global loads for tile kt+1 are
// in flight into registers; at the top of iter kt+1 they are ds_written to
// the same LDS addresses gl2lds used. Barriers: lgkmcnt(0)+s_barrier only;
// NO vmcnt(0) in the main loop. Prologue: tile 0 via gl2lds, then issue
// prefetch(1), then counted vmcnt = waits the gl2lds set only.
//
// MODE 0: rk epilogue, ALL LAYERS batched: blockIdx.z = layer*2+group;
//         A = r_bf (+group), Bt = rnetT base (+layer), p0 = rkb bf16
//         [layer][group][head][1024][64].
// MODE 1: qkv split    -> Qw(+rwb) Qr(+rrb) Kb Vb bf16 (p0..p3,p4,p5)
// MODE 2: + residual   -> f32 p0 = C + p1
// MODE 3: + res + bias -> f32 p0 = C + p1 + bias(p2)
// MODE 4: bias + relu  -> bf16 p0 = relu(C + bias(p1))
// ---------------------------------------------------------------------------
template <int MODE, int TN>
__launch_bounds__(256) __global__
void gemm_bt(const u16* __restrict__ A, const u16* __restrict__ Bt,
             int M, int N, int K,
             void* p0, void* p1, void* p2, void* p3,
             const float* __restrict__ p4, const float* __restrict__ p5) {
  (void)M;
  constexpr int NT = TN / 32;   // n-tiles (16 wide) per wave
  constexpr int NBQ = TN / 32;  // B staging instrs per wave (4 or 2)
  __shared__ u16 As[8192];
  __shared__ u16 Bs[TN * 64];
  const int tid = threadIdx.x;
  const int lane = tid & 63;
  const int w = tid >> 6;
  const int quad = lane >> 4, l15 = lane & 15;
  const int m0 = blockIdx.y << 7, n0 = blockIdx.x * TN;

  if constexpr (MODE == 0) {
    const int lz = blockIdx.z >> 1, gz = blockIdx.z & 1;
    A += (size_t)gz * 524288;          // group offset in r_bf
    Bt += (size_t)lz * 262144;         // per-layer rnetT
    p0 = (void*)((u16*)p0 + (size_t)lz * 1048576 + (size_t)gz * 524288);
  }

  f32x4 acc[4][NT];
#pragma unroll
  for (int a = 0; a < 4; ++a)
#pragma unroll
    for (int b = 0; b < NT; ++b) {
      f32x4 z = {0.f, 0.f, 0.f, 0.f};
      acc[a][b] = z;
    }

  // Staging geometry: per instr, wave w covers 8 rows (8 x 64 u16 = 1 KB).
  const int rg = lane >> 3;
  const int cz = ((lane & 7) ^ rg) << 3;  // swizzled u16 col offset
  const u16* gA = A + (size_t)(m0 + w * 8 + rg) * K + cz;
  const u16* gB = Bt + (size_t)(n0 + w * 8 + rg) * K + cz;
  u16* lA = &As[w * 512];
  u16* lB = &Bs[w * 512];

  const int wm = (w >> 1) << 6, wn = (w & 1) * (NT * 16);
  const int rsw = l15 & 7;  // fragment row&7 (wm, t*16 are multiples of 8)
  const int nk = K >> 6;

  // Prefetch registers for tile kt+1.
  s16x8 pA[4], pB[NBQ];
  auto prefetch = [&](int kt) {
    const int k0 = kt << 6;
#pragma unroll
    for (int q = 0; q < 4; ++q)
      pA[q] = *(const s16x8*)(gA + (size_t)(q * 32) * K + k0);
#pragma unroll
    for (int q = 0; q < NBQ; ++q)
      pB[q] = *(const s16x8*)(gB + (size_t)(q * 32) * K + k0);
  };

  // Prologue: tile 0 via gl2lds, then issue prefetch(1), counted vmcnt.
#pragma unroll
  for (int q = 0; q < 4; ++q)
    gl2lds16(gA + (size_t)(q * 32) * K, lA + q * 2048);
#pragma unroll
  for (int q = 0; q < NBQ; ++q)
    gl2lds16(gB + (size_t)(q * 32) * K, lB + q * 2048);
  asm volatile("" ::: "memory");  // pin: gl2lds issued before prefetch
  __builtin_amdgcn_sched_barrier(0);
  if (nk > 1) {
    prefetch(1);
    if constexpr (NBQ == 4)
      asm volatile("s_waitcnt vmcnt(8)" ::: "memory");  // 8 gl2lds done
    else
      asm volatile("s_waitcnt vmcnt(6)" ::: "memory");  // 6 gl2lds done
  } else {
    asm volatile("s_waitcnt vmcnt(0)" ::: "memory");
  }
  __builtin_amdgcn_s_barrier();
  __builtin_amdgcn_sched_barrier(0);

  for (int kt = 0; kt < nk; ++kt) {
    if (kt > 0) {
      // All waves consumed buffer for kt-1 (ds_reads drained by lgkm+bar).
      FENCE_BAR();
      // Commit prefetched tile kt (same addresses gl2lds used); compiler
      // auto-waits vmcnt on the prefetch regs (landed during compute).
#pragma unroll
      for (int q = 0; q < 4; ++q)
        *(s16x8*)(lA + q * 2048 + lane * 8) = pA[q];
#pragma unroll
      for (int q = 0; q < NBQ; ++q)
        *(s16x8*)(lB + q * 2048 + lane * 8) = pB[q];
      if (kt + 1 < nk) prefetch(kt + 1);
      FENCE_BAR();  // ds_writes visible; next-tile loads stay in flight
    }
#pragma unroll
    for (int ks = 0; ks < 2; ++ks) {
      // global chunk g = ks*4+quad of row r lives at LDS chunk g ^ (r&7)
      const int co = ((ks * 4 + quad) ^ rsw) << 3;
      s16x8 af[4], bfg[NT];
#pragma unroll
      for (int t = 0; t < 4; ++t)
        af[t] = *(const s16x8*)&As[(wm + t * 16 + l15) * 64 + co];
#pragma unroll
      for (int t = 0; t < NT; ++t)
        bfg[t] = *(const s16x8*)&Bs[(wn + t * 16 + l15) * 64 + co];
#pragma unroll
      for (int mt = 0; mt < 4; ++mt)
#pragma unroll
        for (int nt = 0; nt < NT; ++nt)
          acc[mt][nt] = mfma16(af[mt], bfg[nt], acc[mt][nt]);
    }
  }

#pragma unroll
  for (int mt = 0; mt < 4; ++mt) {
#pragma unroll
    for (int nt = 0; nt < NT; ++nt) {
#pragma unroll
      for (int r = 0; r < 4; ++r) {
        const int row = m0 + wm + mt * 16 + quad * 4 + r;
        const int col = n0 + wn + nt * 16 + l15;
        const float v = acc[mt][nt][r];
        if constexpr (MODE == 0) {
          const int hn = col >> 6, d = col & 63;
          ((u16*)p0)[((size_t)hn * 1024 + row) * 64 + d] = f2bf(v);
        } else if constexpr (MODE == 1) {
          const int i = row >> 4, b = row & 15;
          const int which = col >> 9, hn = (col >> 6) & 7, d = col & 63;
          const int bn = b * 8 + hn;
          const size_t idx = ((size_t)bn * 512 + i) * 64 + d;
          if (which == 0) {
            ((u16*)p0)[idx] = f2bf(v + p4[hn * 64 + d]);
            ((u16*)p1)[idx] = f2bf(v + p5[hn * 64 + d]);
          } else if (which == 1) {
            ((u16*)p2)[idx] = f2bf(v);
          } else {
            ((u16*)p3)[idx] = f2bf(v);
          }
        } else if constexpr (MODE == 2) {
          ((float*)p0)[(size_t)row * N + col] =
              v + ((const float*)p1)[(size_t)row * N + col];
        } else if constexpr (MODE == 3) {
          ((float*)p0)[(size_t)row * N + col] =
              v + ((const float*)p1)[(size_t)row * N + col] +
              ((const float*)p2)[col];
        } else {
          float t = v + ((const float*)p1)[col];
          ((u16*)p0)[(size_t)row * N + col] = f2bf(t > 0.f ? t : 0.f);
        }
      }
    }
  }
}

// ---------------------------------------------------------------------------
// Weight transpose+convert: src f32 (R,C) -> dst bf16 (C,R). 64x64 tiles.
// ---------------------------------------------------------------------------
__launch_bounds__(256) __global__
void transpose_w_kernel(const float* __restrict__ qkv, const float* __restrict__ rnet,
                        const float* __restrict__ ow, const float* __restrict__ w1,
                        const float* __restrict__ w2, u16* __restrict__ dst) {
  const int type = blockIdx.z, l = blockIdx.y, tile = blockIdx.x;
  int R, C;
  const float* src;
  u16* out;
  switch (type) {
    case 0: R = 512; C = 1536; src = qkv + (size_t)l * 786432; out = dst + (size_t)l * 786432; break;
    case 1: R = 512; C = 512;  src = rnet + (size_t)l * 262144; out = dst + 3145728 + (size_t)l * 262144; break;
    case 2: R = 512; C = 512;  src = ow + (size_t)l * 262144;   out = dst + 4194304 + (size_t)l * 262144; break;
    case 3: R = 512; C = 2048; src = w1 + (size_t)l * 1048576;  out = dst + 5242880 + (size_t)l * 1048576; break;
    default: R = 2048; C = 512; src = w2 + (size_t)l * 1048576; out = dst + 9437184 + (size_t)l * 1048576; break;
  }
  const int tC = C >> 6;
  const int tR = R >> 6;
  if (tile >= tC * tR) return;
  const int r0 = (tile / tC) << 6, c0 = (tile % tC) << 6;
  __shared__ float tb[64][65];
  const int tid = threadIdx.x;
  const int rr = tid >> 2, cc = (tid & 3) << 4;
#pragma unroll
  for (int j = 0; j < 4; ++j) {
    f32x4 u = *(const f32x4*)(src + (size_t)(r0 + rr) * C + c0 + cc + j * 4);
    tb[rr][cc + j * 4 + 0] = u[0];
    tb[rr][cc + j * 4 + 1] = u[1];
    tb[rr][cc + j * 4 + 2] = u[2];
    tb[rr][cc + j * 4 + 3] = u[3];
  }
  __syncthreads();
  u16x8 o0, o1;
#pragma unroll
  for (int j = 0; j < 8; ++j) o0[j] = f2bf(tb[cc + j][rr]);
#pragma unroll
  for (int j = 0; j < 8; ++j) o1[j] = f2bf(tb[cc + 8 + j][rr]);
  *(u16x8*)(out + (size_t)(c0 + rr) * R + r0 + cc) = o0;
  *(u16x8*)(out + (size_t)(c0 + rr) * R + r0 + cc + 8) = o1;
}

// ---------------------------------------------------------------------------
// Positional embeddings: r_bf[g][j][d], g=0 fw (pos=512-j), g=1 bw (pos=j-512)
// ---------------------------------------------------------------------------
__launch_bounds__(256) __global__
void posemb_kernel(u16* __restrict__ r_bf) {
  const int idx = blockIdx.x * 256 + threadIdx.x;  // 2*1024*512
  const int d = idx & 511, j = (idx >> 9) & 1023, g = idx >> 19;
  const float pos = g ? (float)(j - 512) : (float)(512 - j);
  const int dp = d & 255;
  const float invf = expf((float)dp * (-9.210340371976184f / 256.f));
  const float v = pos * invf;
  r_bf[idx] = f2bf((d < 256) ? sinf(v) : cosf(v));
}

// ---------------------------------------------------------------------------
// V transpose per layer: Vb[bn][j][d] -> Vt[bn][d][j] (bf16), 64-key tiles.
// ---------------------------------------------------------------------------
__launch_bounds__(256) __global__
void transpose_v_kernel(const u16* __restrict__ Vb, u16* __restrict__ Vt) {
  const int bn = blockIdx.y, j0 = blockIdx.x << 6;
  __shared__ u16 tb[64][72];
  const int tid = threadIdx.x;
#pragma unroll
  for (int q = 0; q < 2; ++q) {
    const int s = q * 256 + tid;
    const int jj = s >> 3, c = s & 7;
    u16x8 u = *(const u16x8*)(Vb + ((size_t)bn * 512 + j0 + jj) * 64 + c * 8);
    *(u16x8*)&tb[jj][c * 8] = u;
  }
  __syncthreads();
#pragma unroll
  for (int q = 0; q < 2; ++q) {
    const int s = q * 256 + tid;
    const int d = s >> 3, c = s & 7;
    u16x8 o;
#pragma unroll
    for (int e = 0; e < 8; ++e) o[e] = tb[c * 8 + e][d];
    *(u16x8*)(Vt + ((size_t)bn * 64 + d) * 512 + j0 + c * 8) = o;
  }
}

// ---------------------------------------------------------------------------
// Fused rel-attention, flash-style. Block = one (b,head) x 64 queries; 4 waves.
// LDS = 40960 B -> 4 blocks/CU. Grid (bn, i0): the 8 i0-blocks sharing one
// (b,head)'s K/V/rk get ids === bn (mod 8) -> same XCD -> fetched once, L2-hot.
// PIPELINED (T14 + counted waits), proven rounds 5/7. Unchanged.
// ---------------------------------------------------------------------------
__launch_bounds__(256) __global__
void attn_kernel(const u16* __restrict__ Qw, const u16* __restrict__ Qr,
                 const u16* __restrict__ Kb, const u16* __restrict__ Vt,
                 const u16* __restrict__ rkb, const int* __restrict__ smask,
                 u16* __restrict__ vecb) {
  __shared__ u16 Ks[4096];    // [key][d]   64x64, swizzled
  __shared__ u16 Vts[4096];   // [d][key]   64x64, swizzled
  __shared__ u16 Band[8192];  // [band][d] 128x64, swizzled, 64-row ring
  __shared__ u16 Ps[4096];    // per wave [16][64], XOR-chunk swizzled

  const int tid = threadIdx.x, lane = tid & 63, w = tid >> 6;
  const int quad = lane >> 4, l15 = lane & 15;
  const int bn = blockIdx.x, b = bn >> 3, n = bn & 7;
  const int g = (b >= 8) ? 1 : 0;
  const int i0 = blockIdx.y << 6;

  // Per-thread mask bits: bit s (s=0..31) = smask[b*512 + s*16 + l15] != 0.
  unsigned mbits = 0;
  const int* smb = smask + b * 512 + l15;
#pragma unroll
  for (int s = 0; s < 32; ++s)
    if (smb[s * 16]) mbits |= 1u << s;
  // Wave-uniform valid-tile mask (identical across all 4 waves).
  unsigned vmask = 0;
#pragma unroll
  for (int jt = 0; jt < 8; ++jt)
    if (__any((int)((mbits >> (jt * 4)) & 15u))) vmask |= 1u << jt;
  const int ntiles = vmask ? (32 - __clz((int)vmask)) : 0;

  const u16* qwp = Qw + ((size_t)bn * 512 + i0 + w * 16 + l15) * 64 + quad * 8;
  const u16* qrp = Qr + ((size_t)bn * 512 + i0 + w * 16 + l15) * 64 + quad * 8;
  const s16x8 qw0 = *(const s16x8*)qwp, qw1 = *(const s16x8*)(qwp + 32);
  const s16x8 qr0 = *(const s16x8*)qrp, qr1 = *(const s16x8*)(qrp + 32);

  const u16* kbase = Kb + (size_t)bn * (512 * 64);
  const u16* vbase = Vt + (size_t)bn * (64 * 512);
  const u16* rkg = rkb + (size_t)(g * 8 + n) * (1024 * 64);

  const int s0 = w * 64 + lane;
  const int rl = s0 >> 3;                   // LDS row within 32-row instr
  const int cd = ((s0 & 7) ^ (rl & 7)) * 8; // swizzled data chunk (u16 offset)
  u16* lK0 = &Ks[w * 512];
  u16* lK1 = &Ks[(4 + w) * 512];
  u16* lV0 = &Vts[w * 512];
  u16* lV1 = &Vts[(4 + w) * 512];
  u16* lBq[4] = {&Band[w * 512], &Band[(4 + w) * 512], &Band[(8 + w) * 512],
                 &Band[(12 + w) * 512]};
  u16* pwv = &Ps[w * 1024];

  // fragment-read swizzle: chunk quad -> quad ^ (row&7); row&7 == l15&7 here
  const int sw8 = ((quad ^ (l15 & 7)) * 8);
  const int sw8b = (((quad ^ (l15 & 7)) ^ 4) * 8);

  // rel-shift gather lanes: dest (quad,l15,r) needs band element at
  // k = 15 + nj - mi (nj = t*16+l15, mi = quad*4+r). With e = 15+l15-mi:
  // source tile = t + (e>>4), source lane = quad*16 + (e&15), reg = r.
  int sl[4], hisel[4];
#pragma unroll
  for (int r = 0; r < 4; ++r) {
    const int e = 15 + l15 - quad * 4 - r;
    sl[r] = (quad << 4) | (e & 15);
    hisel[r] = e >> 4;
  }

  f32x4 O[4];
  float m_st[4], l_st[4];
#pragma unroll
  for (int t = 0; t < 4; ++t) {
    f32x4 z = {0.f, 0.f, 0.f, 0.f};
    O[t] = z;
    m_st[t] = -1e30f;
    l_st[t] = 0.f;
  }

  // Prefetch registers for tile jt+1 (K hi/lo, V hi/lo, Band new-64-rows).
  s16x8 rK0, rK1, rV0, rV1, rB0, rB1;
  auto issue_prefetch = [&](int nt) {  // nt = tile index being prefetched
    const int j0n = nt << 6;
    const int jr0n = 449 + j0n - i0;
    rK0 = *(const s16x8*)(kbase + (size_t)(j0n + rl) * 64 + cd);
    rK1 = *(const s16x8*)(kbase + (size_t)(j0n + 32 + rl) * 64 + cd);
    rV0 = *(const s16x8*)(vbase + (size_t)rl * 512 + j0n + cd);
    rV1 = *(const s16x8*)(vbase + (size_t)(rl + 32) * 512 + j0n + cd);
    int rr0 = jr0n + 64 + rl;
    int rr1 = jr0n + 96 + rl;
    rr0 = rr0 < 1023 ? rr0 : 1023;  // last band row unused; avoid OOB
    rr1 = rr1 < 1023 ? rr1 : 1023;
    rB0 = *(const s16x8*)(rkg + (size_t)rr0 * 64 + cd);
    rB1 = *(const s16x8*)(rkg + (size_t)rr1 * 64 + cd);
  };

  for (int jt = 0; jt < ntiles; ++jt) {
    if (jt == 0) {
      // Full stage of tile 0 via gl2lds (no extra registers), then issue
      // tile-1 prefetch, then counted vmcnt: waits the 8 gl2lds only.
      const int jr00 = 449 - i0;
      gl2lds16(kbase + (size_t)rl * 64 + cd, lK0);
      gl2lds16(kbase + (size_t)(32 + rl) * 64 + cd, lK1);
      gl2lds16(vbase + (size_t)rl * 512 + cd, lV0);
      gl2lds16(vbase + (size_t)(rl + 32) * 512 + cd, lV1);
#pragma unroll
      for (int q = 0; q < 4; ++q) {
        int rrow = jr00 + q * 32 + rl;
        rrow = rrow < 1023 ? rrow : 1023;
        gl2lds16(rkg + (size_t)rrow * 64 + cd, lBq[q]);
      }
      asm volatile("" ::: "memory");  // pin: gl2lds issued before prefetch
      __builtin_amdgcn_sched_barrier(0);
      if (ntiles > 1) {
        issue_prefetch(1);
        asm volatile("s_waitcnt vmcnt(6)" ::: "memory");  // 8 gl2lds done
      } else {
        asm volatile("s_waitcnt vmcnt(0)" ::: "memory");
      }
      __builtin_amdgcn_s_barrier();
      __builtin_amdgcn_sched_barrier(0);
    } else {
      // All waves finished reading LDS for jt-1 (every ds_read was consumed
      // by an MFMA before this point).
      FENCE_BAR();
      // Commit prefetched tile jt to LDS (same addresses gl2lds used).
      *(s16x8*)(lK0 + lane * 8) = rK0;
      *(s16x8*)(lK1 + lane * 8) = rK1;
      *(s16x8*)(lV0 + lane * 8) = rV0;
      *(s16x8*)(lV1 + lane * 8) = rV1;
      const int segb = ((jt + 1) & 1) << 1;  // ring segments for new rows
      *(s16x8*)(lBq[segb] + lane * 8) = rB0;
      *(s16x8*)(lBq[segb + 1] + lane * 8) = rB1;
      if (jt + 1 < ntiles) issue_prefetch(jt + 1);
      FENCE_BAR();  // lgkmcnt(0): ds_writes visible; loads stay in flight
    }

    // AC = (q+rwb) . K^T
    f32x4 ac[4];
#pragma unroll
    for (int t = 0; t < 4; ++t) {
      f32x4 z = {0.f, 0.f, 0.f, 0.f};
      ac[t] = z;
      s16x8 k0f = *(const s16x8*)&Ks[(t * 16 + l15) * 64 + sw8];
      s16x8 k1f = *(const s16x8*)&Ks[(t * 16 + l15) * 64 + sw8b];
      ac[t] = mfma16(qw0, k0f, ac[t]);
      ac[t] = mfma16(qw1, k1f, ac[t]);
    }
    // BD band: wave w covers band rows [48-16w, 128-16w), ring-offset reads
    const int bb0 = 48 - w * 16;
    const int rofs = (jt & 1) << 6;
    f32x4 bd[5];
#pragma unroll
    for (int t = 0; t < 5; ++t) {
      f32x4 z = {0.f, 0.f, 0.f, 0.f};
      const int prow = ((bb0 + t * 16 + l15) + rofs) & 127;
      s16x8 b0f = *(const s16x8*)&Band[prow * 64 + sw8];
      s16x8 b1f = *(const s16x8*)&Band[prow * 64 + sw8b];
      bd[t] = mfma16(qr1, b1f, mfma16(qr0, b0f, z));
    }
    // rel-shift via in-quad bpermute; sh[t] doubles as hi of tile t-1
    float sh[5][4];
#pragma unroll
    for (int t = 0; t < 5; ++t)
#pragma unroll
      for (int r = 0; r < 4; ++r) sh[t][r] = __shfl(bd[t][r], sl[r]);

    // combine + scale + mask
    float pv[4][4];
#pragma unroll
    for (int t = 0; t < 4; ++t) {
      const float mk = ((mbits >> (jt * 4 + t)) & 1u) ? 0.f : -1e9f;
#pragma unroll
      for (int r = 0; r < 4; ++r) {
        const float bdv = hisel[r] ? sh[t + 1][r] : sh[t][r];
        pv[t][r] = (ac[t][r] + bdv) * 0.125f + mk;
      }
    }
    // online softmax per C-row (16-lane butterfly within l15 group)
#pragma unroll
    for (int r = 0; r < 4; ++r) {
      float mx = fmaxf(fmaxf(pv[0][r], pv[1][r]), fmaxf(pv[2][r], pv[3][r]));
#pragma unroll
      for (int xm = 1; xm < 16; xm <<= 1) mx = fmaxf(mx, __shfl_xor(mx, xm));
      const float mn = fmaxf(m_st[r], mx);
      const float al = __expf(m_st[r] - mn);
      m_st[r] = mn;
      float rs = 0.f;
#pragma unroll
      for (int t = 0; t < 4; ++t) {
        pv[t][r] = __expf(pv[t][r] - mn);
        rs += pv[t][r];
      }
#pragma unroll
      for (int xm = 1; xm < 16; xm <<= 1) rs += __shfl_xor(rs, xm);
      l_st[r] = l_st[r] * al + rs;
#pragma unroll
      for (int t = 0; t < 4; ++t) O[t][r] *= al;
    }
    // P -> LDS ([16][64] XOR-chunk swizzled), PV MFMA. Ps is per-wave
    // private, so same-wave DS ordering makes this race-free.
#pragma unroll
    for (int t = 0; t < 4; ++t)
#pragma unroll
      for (int r = 0; r < 4; ++r) {
        const int row = quad * 4 + r, col = t * 16 + l15;
        pwv[row * 64 + ((((col >> 3) ^ row) & 7) << 3) + (col & 7)] =
            f2bf(pv[t][r]);
      }
#pragma unroll
    for (int ks = 0; ks < 2; ++ks) {
      const int ch = (((ks * 4 + quad) ^ l15) & 7) << 3;
      s16x8 pf = *(const s16x8*)&pwv[l15 * 64 + ch];
#pragma unroll
      for (int td = 0; td < 4; ++td) {
        s16x8 vf = *(const s16x8*)&Vts[(td * 16 + l15) * 64 +
                                       (ks == 0 ? sw8 : sw8b)];
        O[td] = mfma16(pf, vf, O[td]);
      }
    }
  }

#pragma unroll
  for (int td = 0; td < 4; ++td) {
#pragma unroll
    for (int r = 0; r < 4; ++r) {
      const int i = i0 + w * 16 + quad * 4 + r;
      const float val = O[td][r] / l_st[r];
      vecb[((size_t)i * 16 + b) * 512 + n * 64 + td * 16 + l15] = f2bf(val);
    }
  }
}

// ---------------------------------------------------------------------------
// LayerNorm over D=512, 1 wave per row. row = i*B+b. Optional outputs:
// dst32 f32 (T,B,D), dstbf bf16 (T,B,D), o1/o2 f32 (B,T,D) (for d_out).
// ---------------------------------------------------------------------------
__launch_bounds__(256) __global__
void ln_kernel(const float* __restrict__ src, int src_is_bt,
               const float* __restrict__ gw, const float* __restrict__ bww,
               float* __restrict__ dst32, u16* __restrict__ dstbf,
               float* __restrict__ o1, float* __restrict__ o2) {
  const int row = blockIdx.x * 4 + (threadIdx.x >> 6);
  const int lane = threadIdx.x & 63;
  const int i = row >> 4, b = row & 15;
  const float* x = src + (src_is_bt ? ((size_t)b * 512 + i) * 512 : (size_t)row * 512);
  f32x4 u0 = *(const f32x4*)(x + lane * 8);
  f32x4 u1 = *(const f32x4*)(x + lane * 8 + 4);
  float s = u0[0] + u0[1] + u0[2] + u0[3] + u1[0] + u1[1] + u1[2] + u1[3];
  float sq = u0[0] * u0[0] + u0[1] * u0[1] + u0[2] * u0[2] + u0[3] * u0[3] +
             u1[0] * u1[0] + u1[1] * u1[1] + u1[2] * u1[2] + u1[3] * u1[3];
  for (int m = 1; m < 64; m <<= 1) {
    s += __shfl_xor(s, m);
    sq += __shfl_xor(sq, m);
  }
  const float mean = s * (1.f / 512.f);
  const float var = sq * (1.f / 512.f) - mean * mean;
  const float rs = rsqrtf(var + 1e-6f);
  f32x4 g0 = *(const f32x4*)(gw + lane * 8);
  f32x4 g1 = *(const f32x4*)(gw + lane * 8 + 4);
  f32x4 b0 = *(const f32x4*)(bww + lane * 8);
  f32x4 b1 = *(const f32x4*)(bww + lane * 8 + 4);
  f32x4 y0, y1;
#pragma unroll
  for (int k = 0; k < 4; ++k) {
    y0[k] = (u0[k] - mean) * rs * g0[k] + b0[k];
    y1[k] = (u1[k] - mean) * rs * g1[k] + b1[k];
  }
  const size_t o_ib = (size_t)row * 512 + lane * 8;
  const size_t o_tb = ((size_t)b * 512 + i) * 512 + lane * 8;
  if (dst32) {
    *(f32x4*)(dst32 + o_ib) = y0;
    *(f32x4*)(dst32 + o_ib + 4) = y1;
  }
  if (dstbf) {
    u16x8 ov;
#pragma unroll
    for (int k = 0; k < 4; ++k) {
      ov[k] = f2bf(y0[k]);
      ov[k + 4] = f2bf(y1[k]);
    }
    *(u16x8*)(dstbf + o_ib) = ov;
  }
  if (o1) {
    *(f32x4*)(o1 + o_tb) = y0;
    *(f32x4*)(o1 + o_tb + 4) = y1;
  }
  if (o2) {
    *(f32x4*)(o2 + o_tb) = y0;
    *(f32x4*)(o2 + o_tb + 4) = y1;
  }
}

// ---------------------------------------------------------------------------
extern "C" void kernel_launch(void* const* d_in, const int* in_sizes, int n_in,
                              void* d_out, int out_size, void* d_ws, size_t ws_size,
                              hipStream_t stream) {
  (void)in_sizes; (void)n_in; (void)out_size; (void)ws_size;
  const float* h_in = (const float*)d_in[0];
  const int* smask = (const int*)d_in[1];  // bool -> int32 per harness contract
  const float* rwb = (const float*)d_in[2];
  const float* rrb = (const float*)d_in[3];
  const float* top_g = (const float*)d_in[4];
  const float* top_b = (const float*)d_in[5];
  const float* qkv_w = (const float*)d_in[6];
  const float* rnet_w = (const float*)d_in[7];
  const float* o_w = (const float*)d_in[8];
  const float* attn_g = (const float*)d_in[9];
  const float* attn_b = (const float*)d_in[10];
  const float* w1 = (const float*)d_in[11];
  const float* b1 = (const float*)d_in[12];
  const float* w2 = (const float*)d_in[13];
  const float* b2 = (const float*)d_in[14];
  const float* ff_g = (const float*)d_in[15];
  const float* ff_b = (const float*)d_in[16];
  float* out = (float*)d_out;
  const size_t BTD = 4194304;  // 16*512*512

  char* ws = (char*)d_ws;
  size_t off = 0;
  auto alloc = [&](size_t bytes) {
    void* p = ws + off;
    off += (bytes + 255) & ~(size_t)255;
    return p;
  };
  u16* wT = (u16*)alloc(13631488ull * 2);       // transposed bf16 weights
  u16* r_bf = (u16*)alloc(2ull * 1024 * 512 * 2);
  u16* rkb = (u16*)alloc(8ull << 20);           // 4 layers x 2 groups x 8 x 1024 x 64 bf16
  u16* Qw = (u16*)alloc(8ull << 20);
  u16* Qr = (u16*)alloc(8ull << 20);
  u16* Kb = (u16*)alloc(8ull << 20);
  u16* Vt = (u16*)alloc(8ull << 20);
  u16* vecb = (u16*)alloc(8ull << 20);
  u16* Xbf = (u16*)alloc(8ull << 20);
  u16* ffbf = (u16*)alloc(32ull << 20);
  float* hcur = (float*)alloc(16ull << 20);
  // aliases (lifetimes verified): tmp over Qw+Qr, mid over Kb+Vt, Vb over ffbf[0:8MB]
  float* tmp = (float*)Qw;
  float* mid = (float*)Kb;
  u16* Vb = ffbf;

  dim3 blk(256);
  transpose_w_kernel<<<dim3(256, 4, 5), blk, 0, stream>>>(qkv_w, rnet_w, o_w, w1, w2, wT);
  posemb_kernel<<<dim3(4096), blk, 0, stream>>>(r_bf);
  ln_kernel<<<dim3(2048), blk, 0, stream>>>(h_in, 1, top_g, top_b, hcur, Xbf,
                                            out + BTD, (float*)nullptr);

  // All 4 layers' rk GEMMs batched (activation-independent): z = layer*2+group
  gemm_bt<0, 64><<<dim3(8, 8, 8), blk, 0, stream>>>(
      r_bf, wT + 3145728, 1024, 512, 512,
      rkb, nullptr, nullptr, nullptr, nullptr, nullptr);

  for (int l = 0; l < 4; ++l) {
    u16* qkvT = wT + (size_t)l * 786432;
    u16* oT = wT + 4194304 + (size_t)l * 262144;
    u16* w1T = wT + 5242880 + (size_t)l * 1048576;
    u16* w2T = wT + 9437184 + (size_t)l * 1048576;

    gemm_bt<1, 64><<<dim3(24, 64), blk, 0, stream>>>(
        Xbf, qkvT, 8192, 1536, 512, Qw, Qr, Kb, Vb, rwb, rrb);

    transpose_v_kernel<<<dim3(8, 128), blk, 0, stream>>>(Vb, Vt);

    attn_kernel<<<dim3(128, 8), blk, 0, stream>>>(
        Qw, Qr, Kb, Vt, rkb + (size_t)l * 1048576, smask, vecb);

    gemm_bt<2, 64><<<dim3(8, 64), blk, 0, stream>>>(
        vecb, oT, 8192, 512, 512, tmp, hcur, nullptr, nullptr, nullptr, nullptr);

    ln_kernel<<<dim3(2048), blk, 0, stream>>>(tmp, 0, attn_g + l * 512, attn_b + l * 512,
                                              mid, Xbf, (float*)nullptr, (float*)nullptr);

    gemm_bt<4, 64><<<dim3(32, 64), blk, 0, stream>>>(
        Xbf, w1T, 8192, 2048, 512, ffbf, (void*)(b1 + (size_t)l * 2048),
        nullptr, nullptr, nullptr, nullptr);

    gemm_bt<3, 64><<<dim3(8, 64), blk, 0, stream>>>(
        ffbf, w2T, 8192, 512, 2048, tmp, mid, (void*)(b2 + (size_t)l * 512),
        nullptr, nullptr, nullptr);

    ln_kernel<<<dim3(2048), blk, 0, stream>>>(
        tmp, 0, ff_g + l * 512, ff_b + l * 512, hcur, Xbf,
        out + (size_t)(2 + l) * BTD, (l == 3) ? out : (float*)nullptr);
  }
}